// Round 5
// baseline (1055.934 us; speedup 1.0000x reference)
//
#include <hip/hip_runtime.h>
#include <cstdint>
#include <cstddef>

// ---------------------------------------------------------------------------
// OptimizedTopMAttention: B=2, N=4096, C=512, H=8, hd=64, TOP_M=128, fp32 I/O.
// Split-precision bf16x2 MFMA for all GEMMs (hh+hl+lh). Attention: streaming
// K-sweep restructured to minimize dependency round-trips: chunk-2 load
// prefetch (1 vmcnt wait / 2 tiles), batched atomic-then-write appends
// (1 lgkm round-trip / chunk), batched 16-wide PV gather. Exact top-128 via
// sampled threshold + histogram + rank select (6.8-sigma margins).
// ---------------------------------------------------------------------------

typedef float f32x4 __attribute__((ext_vector_type(4)));
typedef __bf16 bf16x8 __attribute__((ext_vector_type(8)));
typedef __bf16 bf16x4 __attribute__((ext_vector_type(4)));

#define MFMA16(a, b, c) __builtin_amdgcn_mfma_f32_16x16x32_bf16((a), (b), (c), 0, 0, 0)

static __device__ __forceinline__ void async_ld16(const void* g, void* l) {
  __builtin_amdgcn_global_load_lds(
      (const __attribute__((address_space(1))) unsigned int*)g,
      (__attribute__((address_space(3))) unsigned int*)l, 16, 0, 0);
}

static __device__ __forceinline__ float bf16raw_to_f32(unsigned r) {
  return __uint_as_float(r << 16);
}

// ---------------- split fp32 -> (hi, lo) bf16 ------------------------------
__global__ void k_split(const float* __restrict__ src, __bf16* __restrict__ dh,
                        __bf16* __restrict__ dl, int n) {
  const int i = (blockIdx.x * 256 + threadIdx.x) * 4;
  if (i >= n) return;
  const float4 v = *(const float4*)(src + i);
  bf16x4 h, l;
  h[0] = (__bf16)v.x; l[0] = (__bf16)(v.x - (float)h[0]);
  h[1] = (__bf16)v.y; l[1] = (__bf16)(v.y - (float)h[1]);
  h[2] = (__bf16)v.z; l[2] = (__bf16)(v.z - (float)h[2]);
  h[3] = (__bf16)v.w; l[3] = (__bf16)(v.w - (float)h[3]);
  *(bf16x4*)(dh + i) = h;
  *(bf16x4*)(dl + i) = l;
}

// split + transpose: src[512][N] -> dh/dl [N][512]   (K fixed = 512)
__global__ void k_splitT(const float* __restrict__ src, __bf16* __restrict__ dh,
                         __bf16* __restrict__ dl, int N) {
  const int idx = blockIdx.x * 256 + threadIdx.x;
  const int k = idx & 511;
  const int n = idx >> 9;
  if (n >= N) return;
  const float v = src[(size_t)k * N + n];
  const __bf16 hi = (__bf16)v;
  dh[idx] = hi;
  dl[idx] = (__bf16)(v - (float)hi);
}

// ---------------- split-precision GEMM:  C[M][N] = A[M][K] @ B[N][K]^T ------
// MODE 0: QKV epilogue (scatter q*0.125 hi/lo, k hi/lo, v bf16)
// MODE 1: proj epilogue (+bias, fp32 out)
template <int MODE>
__global__ __launch_bounds__(256, 2) void k_gemm(
    const __bf16* __restrict__ Agh, const __bf16* __restrict__ Agl,
    const __bf16* __restrict__ Bgh, const __bf16* __restrict__ Bgl,
    const float* __restrict__ bias, float* __restrict__ Cout,
    __bf16* __restrict__ qh, __bf16* __restrict__ ql,
    __bf16* __restrict__ kh, __bf16* __restrict__ kl,
    __bf16* __restrict__ vv, int N, int K) {
  __shared__ __bf16 sAh[4096], sAl[4096], sBh[4096], sBl[4096];

  const int tid = threadIdx.x;
  const int lane = tid & 63;
  const int wave = tid >> 6;
  const int wm = wave >> 1, wn = wave & 1;
  const int row0 = blockIdx.x * 128;
  const int col0 = blockIdx.y * 128;
  const int m15 = lane & 15, q4 = lane >> 4;

  f32x4 acc[4][4] = {};

  for (int k0 = 0; k0 < K; k0 += 32) {
    __syncthreads();
#pragma unroll
    for (int c = 0; c < 2; ++c) {
      const int s = c * 4 + wave;
      const int gr = s * 16 + m15;
      const int gk = k0 + q4 * 8;
      const size_t aoff = (size_t)(row0 + gr) * K + gk;
      const size_t boff = (size_t)(col0 + gr) * K + gk;
      const int lb = s * 512;
      async_ld16(Agh + aoff, sAh + lb);
      async_ld16(Agl + aoff, sAl + lb);
      async_ld16(Bgh + boff, sBh + lb);
      async_ld16(Bgl + boff, sBl + lb);
    }
    __syncthreads();

    bf16x8 afh[4], afl[4];
#pragma unroll
    for (int mt = 0; mt < 4; ++mt) {
      const int o = (wm * 4 + mt) * 512 + lane * 8;
      afh[mt] = *(const bf16x8*)(sAh + o);
      afl[mt] = *(const bf16x8*)(sAl + o);
    }
#pragma unroll
    for (int nt = 0; nt < 4; ++nt) {
      const int o = (wn * 4 + nt) * 512 + lane * 8;
      const bf16x8 bfh = *(const bf16x8*)(sBh + o);
      const bf16x8 bfl = *(const bf16x8*)(sBl + o);
#pragma unroll
      for (int mt = 0; mt < 4; ++mt) {
        acc[mt][nt] = MFMA16(afh[mt], bfh, acc[mt][nt]);
        acc[mt][nt] = MFMA16(afh[mt], bfl, acc[mt][nt]);
        acc[mt][nt] = MFMA16(afl[mt], bfh, acc[mt][nt]);
      }
    }
  }

#pragma unroll
  for (int mt = 0; mt < 4; ++mt) {
#pragma unroll
    for (int nt = 0; nt < 4; ++nt) {
      const int col = col0 + wn * 64 + nt * 16 + m15;
      const float bcol = bias[col];
#pragma unroll
      for (int r = 0; r < 4; ++r) {
        const int row = row0 + wm * 64 + mt * 16 + q4 * 4 + r;
        const float val = acc[mt][nt][r] + bcol;
        if (MODE == 1) {
          Cout[(size_t)row * N + col] = val;
        } else {
          const int t = col >> 9;       // 0=q 1=k 2=v
          const int cc = col & 511;
          const int h = cc >> 6, d = cc & 63;
          const int b = row >> 12, n = row & 4095;
          const size_t o = ((size_t)(b * 8 + h) * 4096 + n) * 64 + d;
          if (t == 2) {
            vv[o] = (__bf16)val;
          } else {
            const float sv = (t == 0) ? val * 0.125f : val;  // fold 1/sqrt(hd)
            const __bf16 hi = (__bf16)sv;
            const __bf16 lo = (__bf16)(sv - (float)hi);
            if (t == 0) { qh[o] = hi; ql[o] = lo; }
            else        { kh[o] = hi; kl[o] = lo; }
          }
        }
      }
    }
  }
}

// ---------------- fused top-M attention (streaming, 2 blocks/CU) -----------
// t0 = mu + 1.45*sd: boundary z128 = 1.862 +- 0.039, t0 noise 0.045 (1024
// samples) -> 6.8-sigma miss margin. E[cnt] = 301 +- 31 -> CAP 512 = +6.8
// sigma overflow margin.
#define CAP 512
#define NBIN 128
__global__ __launch_bounds__(1024, 8) void k_attn(
    const __bf16* __restrict__ qh, const __bf16* __restrict__ ql,
    const __bf16* __restrict__ kh, const __bf16* __restrict__ kl,
    const __bf16* __restrict__ vv, __bf16* __restrict__ ah,
    __bf16* __restrict__ al) {
  __shared__ uint2 cand[16][CAP];             // 64 KB {score/p bits, col/off}
  __shared__ unsigned int hist[16][NBIN];     //  8 KB (wave-local regions)
  __shared__ float blist[16][32];             //  2 KB
  __shared__ float rsum[16], rsum2[16], t0s[16], invs[16], mrefs[16];
  __shared__ unsigned int ccnt[16], bcnt[16];

  const int tid = threadIdx.x;
  const int lane = tid & 63;
  const int wave = tid >> 6;
  const int m15 = lane & 15, q4 = lane >> 4;

  // XCD-locality swizzle: XCD x handles bh in {2x, 2x+1}
  const int L = blockIdx.x;
  const int s = L >> 3;
  const int bh = (L & 7) * 2 + (s >> 8);
  const int row0 = (s & 255) * 16;
  const size_t base = (size_t)bh * 4096 * 64;

  if (tid < 16) {
    rsum[tid] = 0.f; rsum2[tid] = 0.f;
    ccnt[tid] = 0; bcnt[tid] = 0;
  }
  __syncthreads();

  // ---- Q fragments (scale folded into stored q) ----
  bf16x8 qfh[2], qfl[2];
  {
    const size_t qo = base + (size_t)(row0 + m15) * 64 + q4 * 8;
    qfh[0] = *(const bf16x8*)(qh + qo);
    qfl[0] = *(const bf16x8*)(ql + qo);
    qfh[1] = *(const bf16x8*)(qh + qo + 32);
    qfl[1] = *(const bf16x8*)(ql + qo + 32);
  }
  const int cbase = wave * 256;
  const __bf16* kh_b = kh + base;
  const __bf16* kl_b = kl + base;

  // ---- Sample phase: 64 cols/wave -> 1024 samples/row; 2 chunks of 2 ----
  {
    float s1[4] = {0.f, 0.f, 0.f, 0.f}, s2[4] = {0.f, 0.f, 0.f, 0.f};
#pragma unroll
    for (int c = 0; c < 2; ++c) {
      const size_t k0 = (size_t)(cbase + (c * 2) * 16 + m15) * 64 + q4 * 8;
      const size_t k1 = (size_t)(cbase + (c * 2 + 1) * 16 + m15) * 64 + q4 * 8;
      const bf16x8 A0 = *(const bf16x8*)(kh_b + k0);
      const bf16x8 A1 = *(const bf16x8*)(kh_b + k0 + 32);
      const bf16x8 A2 = *(const bf16x8*)(kl_b + k0);
      const bf16x8 A3 = *(const bf16x8*)(kl_b + k0 + 32);
      const bf16x8 B0 = *(const bf16x8*)(kh_b + k1);
      const bf16x8 B1 = *(const bf16x8*)(kh_b + k1 + 32);
      const bf16x8 B2 = *(const bf16x8*)(kl_b + k1);
      const bf16x8 B3 = *(const bf16x8*)(kl_b + k1 + 32);
      f32x4 a0 = {0.f, 0.f, 0.f, 0.f}, a1 = {0.f, 0.f, 0.f, 0.f};
      a0 = MFMA16(qfh[0], A0, a0);
      a1 = MFMA16(qfh[0], B0, a1);
      a0 = MFMA16(qfh[1], A1, a0);
      a1 = MFMA16(qfh[1], B1, a1);
      a0 = MFMA16(qfh[0], A2, a0);
      a1 = MFMA16(qfh[0], B2, a1);
      a0 = MFMA16(qfh[1], A3, a0);
      a1 = MFMA16(qfh[1], B3, a1);
      a0 = MFMA16(qfl[0], A0, a0);
      a1 = MFMA16(qfl[0], B0, a1);
      a0 = MFMA16(qfl[1], A1, a0);
      a1 = MFMA16(qfl[1], B1, a1);
#pragma unroll
      for (int r = 0; r < 4; ++r) {
        s1[r] += a0[r] + a1[r];
        s2[r] += a0[r] * a0[r] + a1[r] * a1[r];
      }
    }
#pragma unroll
    for (int o = 1; o < 16; o <<= 1)
#pragma unroll
      for (int r = 0; r < 4; ++r) {
        s1[r] += __shfl_xor(s1[r], o);
        s2[r] += __shfl_xor(s2[r], o);
      }
    if (m15 == 0) {
#pragma unroll
      for (int r = 0; r < 4; ++r) {
        atomicAdd(&rsum[q4 * 4 + r], s1[r]);
        atomicAdd(&rsum2[q4 * 4 + r], s2[r]);
      }
    }
  }
  __syncthreads();
  if (tid < 16) {
    const float mu = rsum[tid] * (1.f / 1024.f);
    float var = rsum2[tid] * (1.f / 1024.f) - mu * mu;
    const float sd = sqrtf(fmaxf(var, 1e-12f));
    t0s[tid] = mu + 1.45f * sd;
    invs[tid] = (float)(NBIN - 1) * 0.999f / (3.55f * sd);  // covers to mu+5sd
    mrefs[tid] = mu + 5.0f * sd;                // exp reference
  }
  __syncthreads();

  float t0r[4];
#pragma unroll
  for (int r = 0; r < 4; ++r) t0r[r] = t0s[q4 * 4 + r];

  // ---- Main sweep: 8 chunks x 2 tiles; 1 vmem RT + 1 lgkm RT per chunk ----
  for (int c = 0; c < 8; ++c) {
    const size_t k0 = (size_t)(cbase + (c * 2) * 16 + m15) * 64 + q4 * 8;
    const size_t k1 = (size_t)(cbase + (c * 2 + 1) * 16 + m15) * 64 + q4 * 8;
    const bf16x8 A0 = *(const bf16x8*)(kh_b + k0);
    const bf16x8 A1 = *(const bf16x8*)(kh_b + k0 + 32);
    const bf16x8 A2 = *(const bf16x8*)(kl_b + k0);
    const bf16x8 A3 = *(const bf16x8*)(kl_b + k0 + 32);
    const bf16x8 B0 = *(const bf16x8*)(kh_b + k1);
    const bf16x8 B1 = *(const bf16x8*)(kh_b + k1 + 32);
    const bf16x8 B2 = *(const bf16x8*)(kl_b + k1);
    const bf16x8 B3 = *(const bf16x8*)(kl_b + k1 + 32);
    f32x4 a0 = {0.f, 0.f, 0.f, 0.f}, a1 = {0.f, 0.f, 0.f, 0.f};
    a0 = MFMA16(qfh[0], A0, a0);
    a1 = MFMA16(qfh[0], B0, a1);
    a0 = MFMA16(qfh[1], A1, a0);
    a1 = MFMA16(qfh[1], B1, a1);
    a0 = MFMA16(qfh[0], A2, a0);
    a1 = MFMA16(qfh[0], B2, a1);
    a0 = MFMA16(qfh[1], A3, a0);
    a1 = MFMA16(qfh[1], B3, a1);
    a0 = MFMA16(qfl[0], A0, a0);
    a1 = MFMA16(qfl[0], B0, a1);
    a0 = MFMA16(qfl[1], A1, a0);
    a1 = MFMA16(qfl[1], B1, a1);

    // batched append: phase A issues all atomics, phase B all writes
    float sc[8];
#pragma unroll
    for (int r = 0; r < 4; ++r) { sc[r] = a0[r]; sc[4 + r] = a1[r]; }
    bool sel[8];
    unsigned idx[8];
#pragma unroll
    for (int k = 0; k < 8; ++k) {
      const int row = q4 * 4 + (k & 3);
      sel[k] = sc[k] > t0r[k & 3];
      idx[k] = 0u;
      if (sel[k]) idx[k] = atomicAdd(&ccnt[row], 1u);
    }
#pragma unroll
    for (int k = 0; k < 8; ++k) {
      if (sel[k] && idx[k] < CAP) {
        const int row = q4 * 4 + (k & 3);
        const unsigned col = (unsigned)(cbase + (c * 2 + (k >> 2)) * 16 + m15);
        cand[row][idx[k]] = make_uint2(__float_as_uint(sc[k]), col);
      }
    }
  }
  __syncthreads();

  // ---- Per-row epilogue: wave w owns row w; no further barriers ----
  const int row = wave;
  const unsigned cnt = min(ccnt[row], (unsigned)CAP);
  const float t0 = t0s[row], iv = invs[row];

  // build histogram from candidate list (wave-local region)
  hist[row][lane] = 0;
  hist[row][lane + 64] = 0;
  for (unsigned i = lane; i < cnt; i += 64) {
    const float v = __uint_as_float(cand[row][i].x);
    int b = (int)((v - t0) * iv);
    b = b < 0 ? 0 : (b > NBIN - 1 ? NBIN - 1 : b);
    atomicAdd(&hist[row][b], 1u);
  }

  // suffix scan of 128 bins (lane owns bins 2l, 2l+1)
  const unsigned h0 = hist[row][2 * lane];
  const unsigned h1 = hist[row][2 * lane + 1];
  unsigned S = h0 + h1;
  for (int o = 1; o < 64; o <<= 1) {
    const unsigned tmp = __shfl_down(S, o);
    if (lane + o < 64) S += tmp;
  }
  unsigned Snext = __shfl_down(S, 1);
  if (lane == 63) Snext = 0;
  const bool owner = (S >= 128u) && (Snext < 128u);
  const unsigned long long msk = __ballot(owner);
  float thr = -3.0e38f;
  if (msk != 0ull) {
    const int ol = __ffsll((unsigned long long)msk) - 1;
    int Bv = 0;
    unsigned rv = 128;
    if (owner) {
      unsigned cab = Snext;
      if (cab + h1 >= 128u) { Bv = 2 * lane + 1; rv = 128u - cab; }
      else { cab += h1; Bv = 2 * lane; rv = 128u - cab; }
    }
    const int B = __shfl(Bv, ol);
    const unsigned rneed = (unsigned)__shfl((int)rv, ol);
    // collect threshold-bin values
    for (unsigned i = lane; i < cnt; i += 64) {
      const float v = __uint_as_float(cand[row][i].x);
      int b = (int)((v - t0) * iv);
      b = b < 0 ? 0 : (b > NBIN - 1 ? NBIN - 1 : b);
      if (b == B) {
        const unsigned j = atomicAdd(&bcnt[row], 1u);
        if (j < 32) blist[row][j] = v;
      }
    }
    const unsigned ml = min(bcnt[row], 32u);
    const float myv = (lane < (int)ml) ? blist[row][lane] : 0.f;
    unsigned rlt = 0, req = 0;
    for (unsigned j = 0; j < ml; ++j) {
      const float w2 = blist[row][j];
      rlt += (w2 > myv) ? 1u : 0u;
      req += (w2 == myv) ? 1u : 0u;
    }
    const bool hit = (lane < (int)ml) && (rlt < rneed) && (rlt + req >= rneed);
    const unsigned long long hm = __ballot(hit);
    if (hm != 0ull) thr = __shfl(myv, __ffsll((unsigned long long)hm) - 1);
  }

  // ---- compact (v >= thr): store {p_bits, byte_off}; accumulate z ----
  const float mref = mrefs[row];
  unsigned outc = 0;
  float zpart = 0.f;
  for (unsigned c = 0; c * 64 < cnt; ++c) {
    const unsigned i = c * 64 + lane;
    bool sl = false;
    float v = 0.f;
    unsigned cc = 0;
    if (i < cnt) {
      const uint2 e = cand[row][i];
      v = __uint_as_float(e.x);
      cc = e.y;
      sl = (v >= thr);
    }
    const unsigned long long mb = __ballot(sl);
    if (sl) {
      const unsigned pos = outc + (unsigned)__popcll(mb & ((1ull << lane) - 1ull));
      const float p = __expf(v - mref);
      zpart += p;
      cand[row][pos] = make_uint2(__float_as_uint(p), cc << 7);  // byte offset
    }
    outc += (unsigned)__popcll(mb);
  }
#pragma unroll
  for (int o = 1; o < 64; o <<= 1) zpart += __shfl_xor(zpart, o);
  const int n = (int)outc;

  // ---- sparse PV gather: batches of 16 (1 vmem RT per 16 cols) ----
  {
    const char* vb2 = (const char*)(vv + base) + lane * 2;  // lane = dim
    float o8[8] = {0.f, 0.f, 0.f, 0.f, 0.f, 0.f, 0.f, 0.f};
    int i = 0;
    for (; i + 16 <= n; i += 16) {
      uint2 e[16];
#pragma unroll
      for (int k = 0; k < 16; ++k) e[k] = cand[row][i + k];
      unsigned short raw[16];
#pragma unroll
      for (int k = 0; k < 16; ++k)
        raw[k] = *(const unsigned short*)(vb2 + e[k].y);
#pragma unroll
      for (int k = 0; k < 16; ++k)
        o8[k & 7] += __uint_as_float(e[k].x) * bf16raw_to_f32((unsigned)raw[k]);
    }
    for (; i < n; ++i) {
      const uint2 e = cand[row][i];
      const unsigned rr = *(const unsigned short*)(vb2 + e.y);
      o8[0] += __uint_as_float(e.x) * bf16raw_to_f32(rr);
    }
    const float tot = ((o8[0] + o8[1]) + (o8[2] + o8[3])) +
                      ((o8[4] + o8[5]) + (o8[6] + o8[7]));
    const float outv = tot / fmaxf(zpart, 1e-30f);
    const int b = bh >> 3, hh2 = bh & 7;
    const size_t off = ((size_t)(b * 4096 + row0 + row)) * 512 + hh2 * 64 + lane;
    const __bf16 hi = (__bf16)outv;
    ah[off] = hi;
    al[off] = (__bf16)(outv - (float)hi);
  }
}

// ---------------------------------------------------------------------------
extern "C" void kernel_launch(void* const* d_in, const int* in_sizes, int n_in,
                              void* d_out, int out_size, void* d_ws, size_t ws_size,
                              hipStream_t stream) {
  const float* x      = (const float*)d_in[0];
  const float* qkv_w  = (const float*)d_in[1];
  const float* qkv_b  = (const float*)d_in[2];
  const float* proj_w = (const float*)d_in[3];
  const float* proj_b = (const float*)d_in[4];
  float* out = (float*)d_out;

  char* w = (char*)d_ws;
  __bf16* xh  = (__bf16*)(w + 0);          // 8 MiB  (reused as attn_out hi)
  __bf16* xl  = (__bf16*)(w + 8388608);    // 8 MiB  (reused as attn_out lo)
  __bf16* wqh = (__bf16*)(w + 16777216);   // 1.5 MiB  qkv_w^T hi [1536][512]
  __bf16* wql = (__bf16*)(w + 18350080);
  __bf16* wph = (__bf16*)(w + 19922944);   // 0.5 MiB  proj_w^T hi [512][512]
  __bf16* wpl = (__bf16*)(w + 20447232);
  __bf16* Qh  = (__bf16*)(w + 20971520);   // 8 MiB each: [16][4096][64]
  __bf16* Ql  = (__bf16*)(w + 29360128);
  __bf16* Kh  = (__bf16*)(w + 37748736);
  __bf16* Kl  = (__bf16*)(w + 46137344);
  __bf16* Vv  = (__bf16*)(w + 54525952);   // 8 MiB bf16

  // 1) split inputs
  k_split<<<4096, 256, 0, stream>>>(x, xh, xl, 4194304);
  k_splitT<<<(1536 * 512) / 256, 256, 0, stream>>>(qkv_w, wqh, wql, 1536);
  k_splitT<<<(512 * 512) / 256, 256, 0, stream>>>(proj_w, wph, wpl, 512);

  // 2) QKV GEMM (scatter epilogue)
  {
    dim3 g(64, 12);
    k_gemm<0><<<g, 256, 0, stream>>>(xh, xl, wqh, wql, qkv_b, nullptr,
                                     Qh, Ql, Kh, Kl, Vv, 1536, 512);
  }

  // 3) fused top-128 attention (writes split attn_out into xh/xl)
  k_attn<<<4096, 1024, 0, stream>>>(Qh, Ql, Kh, Kl, Vv, xh, xl);

  // 4) output projection
  {
    dim3 g(64, 4);
    k_gemm<1><<<g, 256, 0, stream>>>(xh, xl, wph, wpl, proj_b, out,
                                     nullptr, nullptr, nullptr, nullptr, nullptr,
                                     512, 512);
  }
}

// Round 6
// 1013.448 us; speedup vs baseline: 1.0419x; 1.0419x over previous
//
#include <hip/hip_runtime.h>
#include <cstdint>
#include <cstddef>

// ---------------------------------------------------------------------------
// OptimizedTopMAttention: B=2, N=4096, C=512, H=8, hd=64, TOP_M=128, fp32 I/O.
// Split-precision bf16x2 MFMA for all GEMMs (hh+hl+lh). Attention redesigned
// around the DS-pipe bottleneck: transposed QK MFMA (lane holds 4 cols of ONE
// row) -> register-buffered appends flushed with one LDS atomic + ballot
// prefix per 4-tile window; 4-col-group PV gather (1 broadcast ds_read per
// 4 cols). Exact top-128 via sampled threshold + histogram + rank select.
// ---------------------------------------------------------------------------

typedef float f32x4 __attribute__((ext_vector_type(4)));
typedef __bf16 bf16x8 __attribute__((ext_vector_type(8)));
typedef __bf16 bf16x4 __attribute__((ext_vector_type(4)));

#define MFMA16(a, b, c) __builtin_amdgcn_mfma_f32_16x16x32_bf16((a), (b), (c), 0, 0, 0)

static __device__ __forceinline__ void async_ld16(const void* g, void* l) {
  __builtin_amdgcn_global_load_lds(
      (const __attribute__((address_space(1))) unsigned int*)g,
      (__attribute__((address_space(3))) unsigned int*)l, 16, 0, 0);
}

static __device__ __forceinline__ float bf16raw_to_f32(unsigned r) {
  return __uint_as_float(r << 16);
}

// ---------------- split fp32 -> (hi, lo) bf16 ------------------------------
__global__ void k_split(const float* __restrict__ src, __bf16* __restrict__ dh,
                        __bf16* __restrict__ dl, int n) {
  const int i = (blockIdx.x * 256 + threadIdx.x) * 4;
  if (i >= n) return;
  const float4 v = *(const float4*)(src + i);
  bf16x4 h, l;
  h[0] = (__bf16)v.x; l[0] = (__bf16)(v.x - (float)h[0]);
  h[1] = (__bf16)v.y; l[1] = (__bf16)(v.y - (float)h[1]);
  h[2] = (__bf16)v.z; l[2] = (__bf16)(v.z - (float)h[2]);
  h[3] = (__bf16)v.w; l[3] = (__bf16)(v.w - (float)h[3]);
  *(bf16x4*)(dh + i) = h;
  *(bf16x4*)(dl + i) = l;
}

// split + transpose: src[512][N] -> dh/dl [N][512]   (K fixed = 512)
__global__ void k_splitT(const float* __restrict__ src, __bf16* __restrict__ dh,
                         __bf16* __restrict__ dl, int N) {
  const int idx = blockIdx.x * 256 + threadIdx.x;
  const int k = idx & 511;
  const int n = idx >> 9;
  if (n >= N) return;
  const float v = src[(size_t)k * N + n];
  const __bf16 hi = (__bf16)v;
  dh[idx] = hi;
  dl[idx] = (__bf16)(v - (float)hi);
}

// ---------------- split-precision GEMM:  C[M][N] = A[M][K] @ B[N][K]^T ------
// MODE 0: QKV epilogue (scatter q*0.125 hi/lo, k hi/lo, v bf16)
// MODE 1: proj epilogue (+bias, fp32 out)
template <int MODE>
__global__ __launch_bounds__(256, 2) void k_gemm(
    const __bf16* __restrict__ Agh, const __bf16* __restrict__ Agl,
    const __bf16* __restrict__ Bgh, const __bf16* __restrict__ Bgl,
    const float* __restrict__ bias, float* __restrict__ Cout,
    __bf16* __restrict__ qh, __bf16* __restrict__ ql,
    __bf16* __restrict__ kh, __bf16* __restrict__ kl,
    __bf16* __restrict__ vv, int N, int K) {
  __shared__ __bf16 sAh[4096], sAl[4096], sBh[4096], sBl[4096];

  const int tid = threadIdx.x;
  const int lane = tid & 63;
  const int wave = tid >> 6;
  const int wm = wave >> 1, wn = wave & 1;
  const int row0 = blockIdx.x * 128;
  const int col0 = blockIdx.y * 128;
  const int m15 = lane & 15, q4 = lane >> 4;

  f32x4 acc[4][4] = {};

  for (int k0 = 0; k0 < K; k0 += 32) {
    __syncthreads();
#pragma unroll
    for (int c = 0; c < 2; ++c) {
      const int s = c * 4 + wave;
      const int gr = s * 16 + m15;
      const int gk = k0 + q4 * 8;
      const size_t aoff = (size_t)(row0 + gr) * K + gk;
      const size_t boff = (size_t)(col0 + gr) * K + gk;
      const int lb = s * 512;
      async_ld16(Agh + aoff, sAh + lb);
      async_ld16(Agl + aoff, sAl + lb);
      async_ld16(Bgh + boff, sBh + lb);
      async_ld16(Bgl + boff, sBl + lb);
    }
    __syncthreads();

    bf16x8 afh[4], afl[4];
#pragma unroll
    for (int mt = 0; mt < 4; ++mt) {
      const int o = (wm * 4 + mt) * 512 + lane * 8;
      afh[mt] = *(const bf16x8*)(sAh + o);
      afl[mt] = *(const bf16x8*)(sAl + o);
    }
#pragma unroll
    for (int nt = 0; nt < 4; ++nt) {
      const int o = (wn * 4 + nt) * 512 + lane * 8;
      const bf16x8 bfh = *(const bf16x8*)(sBh + o);
      const bf16x8 bfl = *(const bf16x8*)(sBl + o);
#pragma unroll
      for (int mt = 0; mt < 4; ++mt) {
        acc[mt][nt] = MFMA16(afh[mt], bfh, acc[mt][nt]);
        acc[mt][nt] = MFMA16(afh[mt], bfl, acc[mt][nt]);
        acc[mt][nt] = MFMA16(afl[mt], bfh, acc[mt][nt]);
      }
    }
  }

#pragma unroll
  for (int mt = 0; mt < 4; ++mt) {
#pragma unroll
    for (int nt = 0; nt < 4; ++nt) {
      const int col = col0 + wn * 64 + nt * 16 + m15;
      const float bcol = bias[col];
#pragma unroll
      for (int r = 0; r < 4; ++r) {
        const int row = row0 + wm * 64 + mt * 16 + q4 * 4 + r;
        const float val = acc[mt][nt][r] + bcol;
        if (MODE == 1) {
          Cout[(size_t)row * N + col] = val;
        } else {
          const int t = col >> 9;       // 0=q 1=k 2=v
          const int cc = col & 511;
          const int h = cc >> 6, d = cc & 63;
          const int b = row >> 12, n = row & 4095;
          const size_t o = ((size_t)(b * 8 + h) * 4096 + n) * 64 + d;
          if (t == 2) {
            vv[o] = (__bf16)val;
          } else {
            const float sv = (t == 0) ? val * 0.125f : val;  // fold 1/sqrt(hd)
            const __bf16 hi = (__bf16)sv;
            const __bf16 lo = (__bf16)(sv - (float)hi);
            if (t == 0) { qh[o] = hi; ql[o] = lo; }
            else        { kh[o] = hi; kl[o] = lo; }
          }
        }
      }
    }
  }
}

// ---------------- fused top-M attention (streaming, 2 blocks/CU) -----------
// t0 = mu + 1.45*sd: boundary z128 = 1.862 +- 0.039, t0 noise 0.045 (1024
// samples) -> 6.8-sigma miss margin. E[cnt] = 301 +- 31 -> CAP 512 = +6.8
// sigma overflow margin.
#define CAP 512
#define NBIN 128
__global__ __launch_bounds__(1024, 8) void k_attn(
    const __bf16* __restrict__ qh, const __bf16* __restrict__ ql,
    const __bf16* __restrict__ kh, const __bf16* __restrict__ kl,
    const __bf16* __restrict__ vv, __bf16* __restrict__ ah,
    __bf16* __restrict__ al) {
  __shared__ uint2 cand[16][CAP];             // 64 KB {score/p bits, col/off}
  __shared__ unsigned int hist[16][NBIN];     //  8 KB (wave-local regions)
  __shared__ float blist[16][32];             //  2 KB
  __shared__ float rsum[16], rsum2[16], t0s[16], invs[16], mrefs[16];
  __shared__ unsigned int ccnt[16], bcnt[16];

  const int tid = threadIdx.x;
  const int lane = tid & 63;
  const int wave = tid >> 6;
  const int m15 = lane & 15, q4 = lane >> 4;

  // XCD-locality swizzle: XCD x handles bh in {2x, 2x+1}
  const int L = blockIdx.x;
  const int s = L >> 3;
  const int bh = (L & 7) * 2 + (s >> 8);
  const int row0 = (s & 255) * 16;
  const size_t base = (size_t)bh * 4096 * 64;

  if (tid < 16) {
    rsum[tid] = 0.f; rsum2[tid] = 0.f;
    ccnt[tid] = 0; bcnt[tid] = 0;
  }
  __syncthreads();

  // ---- Q fragments (scale folded into stored q); used as B operand ----
  bf16x8 qfh[2], qfl[2];
  {
    const size_t qo = base + (size_t)(row0 + m15) * 64 + q4 * 8;
    qfh[0] = *(const bf16x8*)(qh + qo);
    qfl[0] = *(const bf16x8*)(ql + qo);
    qfh[1] = *(const bf16x8*)(qh + qo + 32);
    qfl[1] = *(const bf16x8*)(ql + qo + 32);
  }
  const int cbase = wave * 256;
  const __bf16* kh_b = kh + base;
  const __bf16* kl_b = kl + base;

  // ---- Sample phase: 64 cols/wave -> 1024 samples/row -> mu, sigma ----
  // Transposed MFMA: D = K_tile x Q^T -> lane holds 4 cols (q4*4+r) of the
  // SINGLE row m15.
  {
    float s1 = 0.f, s2 = 0.f;
    for (int t = 0; t < 4; ++t) {
      const size_t ko = (size_t)(cbase + t * 16 + m15) * 64 + q4 * 8;
      const bf16x8 ch0 = *(const bf16x8*)(kh_b + ko);
      const bf16x8 cl0 = *(const bf16x8*)(kl_b + ko);
      const bf16x8 ch1 = *(const bf16x8*)(kh_b + ko + 32);
      const bf16x8 cl1 = *(const bf16x8*)(kl_b + ko + 32);
      f32x4 a = {0.f, 0.f, 0.f, 0.f};
      a = MFMA16(ch0, qfh[0], a);
      a = MFMA16(ch1, qfh[1], a);
      a = MFMA16(cl0, qfh[0], a);
      a = MFMA16(cl1, qfh[1], a);
      a = MFMA16(ch0, qfl[0], a);
      a = MFMA16(ch1, qfl[1], a);
#pragma unroll
      for (int r = 0; r < 4; ++r) { s1 += a[r]; s2 += a[r] * a[r]; }
    }
    // reduce over the 4 quads (same m15 = same row)
    s1 += __shfl_xor(s1, 16); s1 += __shfl_xor(s1, 32);
    s2 += __shfl_xor(s2, 16); s2 += __shfl_xor(s2, 32);
    if (q4 == 0) {
      atomicAdd(&rsum[m15], s1);
      atomicAdd(&rsum2[m15], s2);
    }
  }
  __syncthreads();
  if (tid < 16) {
    const float mu = rsum[tid] * (1.f / 1024.f);
    float var = rsum2[tid] * (1.f / 1024.f) - mu * mu;
    const float sd = sqrtf(fmaxf(var, 1e-12f));
    t0s[tid] = mu + 1.45f * sd;
    invs[tid] = (float)(NBIN - 1) * 0.999f / (3.55f * sd);  // covers to mu+5sd
    mrefs[tid] = mu + 5.0f * sd;                // exp reference
  }
  __syncthreads();

  const float t0w = t0s[m15];  // this lane's row threshold
  const unsigned long long bel = (1ull << lane) - 1ull;
  const unsigned long long rowmask = 0x0001000100010001ull << m15;

  // ---- Main sweep: 4 windows x 4 tiles; register-buffered appends ----
  for (int w = 0; w < 4; ++w) {
    uint2 s0v = make_uint2(0, 0), s1v = make_uint2(0, 0), s2v = make_uint2(0, 0);
    int cnt = 0;
    for (int tt = 0; tt < 4; ++tt) {
      const int t = w * 4 + tt;
      const size_t ko = (size_t)(cbase + t * 16 + m15) * 64 + q4 * 8;
      const bf16x8 ch0 = *(const bf16x8*)(kh_b + ko);
      const bf16x8 cl0 = *(const bf16x8*)(kl_b + ko);
      const bf16x8 ch1 = *(const bf16x8*)(kh_b + ko + 32);
      const bf16x8 cl1 = *(const bf16x8*)(kl_b + ko + 32);
      f32x4 a = {0.f, 0.f, 0.f, 0.f};
      a = MFMA16(ch0, qfh[0], a);
      a = MFMA16(ch1, qfh[1], a);
      a = MFMA16(cl0, qfh[0], a);
      a = MFMA16(cl1, qfh[1], a);
      a = MFMA16(ch0, qfl[0], a);
      a = MFMA16(ch1, qfl[1], a);
#pragma unroll
      for (int r = 0; r < 4; ++r) {
        const float sc = a[r];
        if (sc > t0w) {
          const unsigned col = (unsigned)(cbase + t * 16 + q4 * 4 + r);
          const uint2 e = make_uint2(__float_as_uint(sc), col);
          if (cnt == 0) s0v = e;
          else if (cnt == 1) s1v = e;
          else if (cnt == 2) s2v = e;
          else {  // rare overflow: direct append
            const unsigned ix = atomicAdd(&ccnt[m15], 1u);
            if (ix < CAP) cand[m15][ix] = e;
          }
          ++cnt;
        }
      }
    }
    // flush window: one atomic per row (issued by quad0), ballot prefixes
    const unsigned long long b0 = __ballot(cnt > 0);
    const unsigned long long b1 = __ballot(cnt > 1);
    const unsigned long long b2 = __ballot(cnt > 2);
    const unsigned c0 = (unsigned)__popcll(b0 & rowmask);
    const unsigned c1 = (unsigned)__popcll(b1 & rowmask);
    const unsigned c2 = (unsigned)__popcll(b2 & rowmask);
    const unsigned tot = c0 + c1 + c2;
    unsigned bas = 0;
    if (q4 == 0 && tot > 0) bas = atomicAdd(&ccnt[m15], tot);
    bas = __shfl(bas, m15);
    if (cnt > 0) {
      const unsigned u = bas + (unsigned)__popcll(b0 & rowmask & bel);
      if (u < CAP) cand[m15][u] = s0v;
    }
    if (cnt > 1) {
      const unsigned u = bas + c0 + (unsigned)__popcll(b1 & rowmask & bel);
      if (u < CAP) cand[m15][u] = s1v;
    }
    if (cnt > 2) {
      const unsigned u = bas + c0 + c1 + (unsigned)__popcll(b2 & rowmask & bel);
      if (u < CAP) cand[m15][u] = s2v;
    }
  }
  __syncthreads();

  // ---- Per-row epilogue: wave w owns row w; no further barriers ----
  const int row = wave;
  const unsigned cnt = min(ccnt[row], (unsigned)CAP);
  const float t0 = t0s[row], iv = invs[row];

  // build histogram from candidate list (wave-local region)
  hist[row][lane] = 0;
  hist[row][lane + 64] = 0;
  for (unsigned i = lane; i < cnt; i += 64) {
    const float v = __uint_as_float(cand[row][i].x);
    int b = (int)((v - t0) * iv);
    b = b < 0 ? 0 : (b > NBIN - 1 ? NBIN - 1 : b);
    atomicAdd(&hist[row][b], 1u);
  }

  // suffix scan of 128 bins (lane owns bins 2l, 2l+1)
  const unsigned h0 = hist[row][2 * lane];
  const unsigned h1 = hist[row][2 * lane + 1];
  unsigned S = h0 + h1;
  for (int o = 1; o < 64; o <<= 1) {
    const unsigned tmp = __shfl_down(S, o);
    if (lane + o < 64) S += tmp;
  }
  unsigned Snext = __shfl_down(S, 1);
  if (lane == 63) Snext = 0;
  const bool owner = (S >= 128u) && (Snext < 128u);
  const unsigned long long msk = __ballot(owner);
  float thr = -3.0e38f;
  if (msk != 0ull) {
    const int ol = __ffsll((unsigned long long)msk) - 1;
    int Bv = 0;
    unsigned rv = 128;
    if (owner) {
      unsigned cab = Snext;
      if (cab + h1 >= 128u) { Bv = 2 * lane + 1; rv = 128u - cab; }
      else { cab += h1; Bv = 2 * lane; rv = 128u - cab; }
    }
    const int B = __shfl(Bv, ol);
    const unsigned rneed = (unsigned)__shfl((int)rv, ol);
    // collect threshold-bin values
    for (unsigned i = lane; i < cnt; i += 64) {
      const float v = __uint_as_float(cand[row][i].x);
      int b = (int)((v - t0) * iv);
      b = b < 0 ? 0 : (b > NBIN - 1 ? NBIN - 1 : b);
      if (b == B) {
        const unsigned j = atomicAdd(&bcnt[row], 1u);
        if (j < 32) blist[row][j] = v;
      }
    }
    const unsigned ml = min(bcnt[row], 32u);
    const float myv = (lane < (int)ml) ? blist[row][lane] : 0.f;
    unsigned rlt = 0, req = 0;
    for (unsigned j = 0; j < ml; ++j) {
      const float w2 = blist[row][j];
      rlt += (w2 > myv) ? 1u : 0u;
      req += (w2 == myv) ? 1u : 0u;
    }
    const bool hit = (lane < (int)ml) && (rlt < rneed) && (rlt + req >= rneed);
    const unsigned long long hm = __ballot(hit);
    if (hm != 0ull) thr = __shfl(myv, __ffsll((unsigned long long)hm) - 1);
  }

  // ---- compact (v >= thr): store {p_bits, byte_off}; accumulate z ----
  const float mref = mrefs[row];
  unsigned outc = 0;
  float zpart = 0.f;
  for (unsigned c = 0; c * 64 < cnt; ++c) {
    const unsigned i = c * 64 + lane;
    bool sl = false;
    float v = 0.f;
    unsigned cc = 0;
    if (i < cnt) {
      const uint2 e = cand[row][i];
      v = __uint_as_float(e.x);
      cc = e.y;
      sl = (v >= thr);
    }
    const unsigned long long mb = __ballot(sl);
    if (sl) {
      const unsigned pos = outc + (unsigned)__popcll(mb & bel);
      const float p = __expf(v - mref);
      zpart += p;
      cand[row][pos] = make_uint2(__float_as_uint(p), cc << 7);  // byte offset
    }
    outc += (unsigned)__popcll(mb);
  }
#pragma unroll
  for (int o = 1; o < 64; o <<= 1) zpart += __shfl_xor(zpart, o);
  const int n = (int)outc;

  // ---- sparse PV gather: 4 col-groups x 16 dim-quads ----
  // lane = g*16 + h: group g handles cols i+g; lane covers dims h*4..h*4+3.
  {
    const int g = q4, h = m15;
    const char* vb = (const char*)(vv + base) + h * 8;
    float o4[4] = {0.f, 0.f, 0.f, 0.f};
    for (int i = 0; i < n; i += 4) {
      const int idx = i + g;
      const uint2 e = cand[row][idx < n ? idx : 0];
      const float p = (idx < n) ? __uint_as_float(e.x) : 0.f;
      const unsigned long long vr = *(const unsigned long long*)(vb + e.y);
      o4[0] += p * bf16raw_to_f32((unsigned)(vr & 0xFFFFull));
      o4[1] += p * bf16raw_to_f32((unsigned)((vr >> 16) & 0xFFFFull));
      o4[2] += p * bf16raw_to_f32((unsigned)((vr >> 32) & 0xFFFFull));
      o4[3] += p * bf16raw_to_f32((unsigned)((vr >> 48) & 0xFFFFull));
    }
#pragma unroll
    for (int o = 16; o < 64; o <<= 1)
#pragma unroll
      for (int d = 0; d < 4; ++d) o4[d] += __shfl_xor(o4[d], o);
    if (g == 0) {
      const float zi = 1.f / fmaxf(zpart, 1e-30f);
      const int b = bh >> 3, hh2 = bh & 7;
      const size_t off =
          ((size_t)(b * 4096 + row0 + row)) * 512 + hh2 * 64 + h * 4;
      ushort4 hp, lp;
      {
        float f0 = o4[0] * zi, f1 = o4[1] * zi, f2 = o4[2] * zi, f3 = o4[3] * zi;
        __bf16 b0 = (__bf16)f0, b1 = (__bf16)f1, b2 = (__bf16)f2, b3 = (__bf16)f3;
        hp.x = *(unsigned short*)&b0; hp.y = *(unsigned short*)&b1;
        hp.z = *(unsigned short*)&b2; hp.w = *(unsigned short*)&b3;
        __bf16 l0 = (__bf16)(f0 - (float)b0), l1 = (__bf16)(f1 - (float)b1);
        __bf16 l2 = (__bf16)(f2 - (float)b2), l3 = (__bf16)(f3 - (float)b3);
        lp.x = *(unsigned short*)&l0; lp.y = *(unsigned short*)&l1;
        lp.z = *(unsigned short*)&l2; lp.w = *(unsigned short*)&l3;
      }
      *(ushort4*)(ah + off) = hp;
      *(ushort4*)(al + off) = lp;
    }
  }
}

// ---------------------------------------------------------------------------
extern "C" void kernel_launch(void* const* d_in, const int* in_sizes, int n_in,
                              void* d_out, int out_size, void* d_ws, size_t ws_size,
                              hipStream_t stream) {
  const float* x      = (const float*)d_in[0];
  const float* qkv_w  = (const float*)d_in[1];
  const float* qkv_b  = (const float*)d_in[2];
  const float* proj_w = (const float*)d_in[3];
  const float* proj_b = (const float*)d_in[4];
  float* out = (float*)d_out;

  char* w = (char*)d_ws;
  __bf16* xh  = (__bf16*)(w + 0);          // 8 MiB  (reused as attn_out hi)
  __bf16* xl  = (__bf16*)(w + 8388608);    // 8 MiB  (reused as attn_out lo)
  __bf16* wqh = (__bf16*)(w + 16777216);   // 1.5 MiB  qkv_w^T hi [1536][512]
  __bf16* wql = (__bf16*)(w + 18350080);
  __bf16* wph = (__bf16*)(w + 19922944);   // 0.5 MiB  proj_w^T hi [512][512]
  __bf16* wpl = (__bf16*)(w + 20447232);
  __bf16* Qh  = (__bf16*)(w + 20971520);   // 8 MiB each: [16][4096][64]
  __bf16* Ql  = (__bf16*)(w + 29360128);
  __bf16* Kh  = (__bf16*)(w + 37748736);
  __bf16* Kl  = (__bf16*)(w + 46137344);
  __bf16* Vv  = (__bf16*)(w + 54525952);   // 8 MiB bf16

  // 1) split inputs
  k_split<<<4096, 256, 0, stream>>>(x, xh, xl, 4194304);
  k_splitT<<<(1536 * 512) / 256, 256, 0, stream>>>(qkv_w, wqh, wql, 1536);
  k_splitT<<<(512 * 512) / 256, 256, 0, stream>>>(proj_w, wph, wpl, 512);

  // 2) QKV GEMM (scatter epilogue)
  {
    dim3 g(64, 12);
    k_gemm<0><<<g, 256, 0, stream>>>(xh, xl, wqh, wql, qkv_b, nullptr,
                                     Qh, Ql, Kh, Kl, Vv, 1536, 512);
  }

  // 3) fused top-128 attention (writes split attn_out into xh/xl)
  k_attn<<<4096, 1024, 0, stream>>>(Qh, Ql, Kh, Kl, Vv, xh, xl);

  // 4) output projection
  {
    dim3 g(64, 4);
    k_gemm<1><<<g, 256, 0, stream>>>(xh, xl, wph, wpl, proj_b, out,
                                     nullptr, nullptr, nullptr, nullptr, nullptr,
                                     512, 512);
  }
}

// Round 7
// 887.535 us; speedup vs baseline: 1.1897x; 1.1419x over previous
//
#include <hip/hip_runtime.h>
#include <cstdint>
#include <cstddef>

// ---------------------------------------------------------------------------
// OptimizedTopMAttention: B=2, N=4096, C=512, H=8, hd=64, TOP_M=128, fp32 I/O.
// Split-precision bf16x2 MFMA for all GEMMs (hh+hl+lh).
// Attention v7: 64 Q-rows per block (4x K-reuse vs 16-row blocks -> per-CU
// L2 traffic 34 MB -> ~13 MB, the R1-R6 invariant bottleneck). Candidates
// packed to 4 B: (q20<<12)|col12, score quantized over [t0, t0+8sd] (quantum
// 7.6e-6 sd; entries unique -> exact rank-select, no ties). 1 block/CU,
// launch_bounds(1024,4) -> 128 VGPR budget (no spill). Exact top-128 via
// sampled threshold (1024 samples, 6.8-sigma miss margin) + histogram +
// rank select; per-row epilogue; batched PV gather.
// ---------------------------------------------------------------------------

typedef float f32x4 __attribute__((ext_vector_type(4)));
typedef __bf16 bf16x8 __attribute__((ext_vector_type(8)));
typedef __bf16 bf16x4 __attribute__((ext_vector_type(4)));

#define MFMA16(a, b, c) __builtin_amdgcn_mfma_f32_16x16x32_bf16((a), (b), (c), 0, 0, 0)

static __device__ __forceinline__ void async_ld16(const void* g, void* l) {
  __builtin_amdgcn_global_load_lds(
      (const __attribute__((address_space(1))) unsigned int*)g,
      (__attribute__((address_space(3))) unsigned int*)l, 16, 0, 0);
}

static __device__ __forceinline__ float bf16raw_to_f32(unsigned r) {
  return __uint_as_float(r << 16);
}

// ---------------- split fp32 -> (hi, lo) bf16 ------------------------------
__global__ void k_split(const float* __restrict__ src, __bf16* __restrict__ dh,
                        __bf16* __restrict__ dl, int n) {
  const int i = (blockIdx.x * 256 + threadIdx.x) * 4;
  if (i >= n) return;
  const float4 v = *(const float4*)(src + i);
  bf16x4 h, l;
  h[0] = (__bf16)v.x; l[0] = (__bf16)(v.x - (float)h[0]);
  h[1] = (__bf16)v.y; l[1] = (__bf16)(v.y - (float)h[1]);
  h[2] = (__bf16)v.z; l[2] = (__bf16)(v.z - (float)h[2]);
  h[3] = (__bf16)v.w; l[3] = (__bf16)(v.w - (float)h[3]);
  *(bf16x4*)(dh + i) = h;
  *(bf16x4*)(dl + i) = l;
}

// split + transpose: src[512][N] -> dh/dl [N][512]   (K fixed = 512)
__global__ void k_splitT(const float* __restrict__ src, __bf16* __restrict__ dh,
                         __bf16* __restrict__ dl, int N) {
  const int idx = blockIdx.x * 256 + threadIdx.x;
  const int k = idx & 511;
  const int n = idx >> 9;
  if (n >= N) return;
  const float v = src[(size_t)k * N + n];
  const __bf16 hi = (__bf16)v;
  dh[idx] = hi;
  dl[idx] = (__bf16)(v - (float)hi);
}

// ---------------- split-precision GEMM:  C[M][N] = A[M][K] @ B[N][K]^T ------
// MODE 0: QKV epilogue (scatter q*0.125 hi/lo, k hi/lo, v bf16)
// MODE 1: proj epilogue (+bias, fp32 out)
template <int MODE>
__global__ __launch_bounds__(256, 2) void k_gemm(
    const __bf16* __restrict__ Agh, const __bf16* __restrict__ Agl,
    const __bf16* __restrict__ Bgh, const __bf16* __restrict__ Bgl,
    const float* __restrict__ bias, float* __restrict__ Cout,
    __bf16* __restrict__ qh, __bf16* __restrict__ ql,
    __bf16* __restrict__ kh, __bf16* __restrict__ kl,
    __bf16* __restrict__ vv, int N, int K) {
  __shared__ __bf16 sAh[4096], sAl[4096], sBh[4096], sBl[4096];

  const int tid = threadIdx.x;
  const int lane = tid & 63;
  const int wave = tid >> 6;
  const int wm = wave >> 1, wn = wave & 1;
  const int row0 = blockIdx.x * 128;
  const int col0 = blockIdx.y * 128;
  const int m15 = lane & 15, q4 = lane >> 4;

  f32x4 acc[4][4] = {};

  for (int k0 = 0; k0 < K; k0 += 32) {
    __syncthreads();
#pragma unroll
    for (int c = 0; c < 2; ++c) {
      const int s = c * 4 + wave;
      const int gr = s * 16 + m15;
      const int gk = k0 + q4 * 8;
      const size_t aoff = (size_t)(row0 + gr) * K + gk;
      const size_t boff = (size_t)(col0 + gr) * K + gk;
      const int lb = s * 512;
      async_ld16(Agh + aoff, sAh + lb);
      async_ld16(Agl + aoff, sAl + lb);
      async_ld16(Bgh + boff, sBh + lb);
      async_ld16(Bgl + boff, sBl + lb);
    }
    __syncthreads();

    bf16x8 afh[4], afl[4];
#pragma unroll
    for (int mt = 0; mt < 4; ++mt) {
      const int o = (wm * 4 + mt) * 512 + lane * 8;
      afh[mt] = *(const bf16x8*)(sAh + o);
      afl[mt] = *(const bf16x8*)(sAl + o);
    }
#pragma unroll
    for (int nt = 0; nt < 4; ++nt) {
      const int o = (wn * 4 + nt) * 512 + lane * 8;
      const bf16x8 bfh = *(const bf16x8*)(sBh + o);
      const bf16x8 bfl = *(const bf16x8*)(sBl + o);
#pragma unroll
      for (int mt = 0; mt < 4; ++mt) {
        acc[mt][nt] = MFMA16(afh[mt], bfh, acc[mt][nt]);
        acc[mt][nt] = MFMA16(afh[mt], bfl, acc[mt][nt]);
        acc[mt][nt] = MFMA16(afl[mt], bfh, acc[mt][nt]);
      }
    }
  }

#pragma unroll
  for (int mt = 0; mt < 4; ++mt) {
#pragma unroll
    for (int nt = 0; nt < 4; ++nt) {
      const int col = col0 + wn * 64 + nt * 16 + m15;
      const float bcol = bias[col];
#pragma unroll
      for (int r = 0; r < 4; ++r) {
        const int row = row0 + wm * 64 + mt * 16 + q4 * 4 + r;
        const float val = acc[mt][nt][r] + bcol;
        if (MODE == 1) {
          Cout[(size_t)row * N + col] = val;
        } else {
          const int t = col >> 9;       // 0=q 1=k 2=v
          const int cc = col & 511;
          const int h = cc >> 6, d = cc & 63;
          const int b = row >> 12, n = row & 4095;
          const size_t o = ((size_t)(b * 8 + h) * 4096 + n) * 64 + d;
          if (t == 2) {
            vv[o] = (__bf16)val;
          } else {
            const float sv = (t == 0) ? val * 0.125f : val;  // fold 1/sqrt(hd)
            const __bf16 hi = (__bf16)sv;
            const __bf16 lo = (__bf16)(sv - (float)hi);
            if (t == 0) { qh[o] = hi; ql[o] = lo; }
            else        { kh[o] = hi; kl[o] = lo; }
          }
        }
      }
    }
  }
}

// ---------------- fused top-M attention: 64 rows/block, 1 block/CU ---------
// t0 = mu + 1.45*sd (1024 samples): 6.8-sigma miss margin vs z128=1.862.
// E[cnt]=301+-31 -> CAP 496 = +6.3 sigma overflow margin.
// Packed entry: (q<<12)|col, q = (s-t0)/(8*sd) * 2^20 clamped.
#define CAP 496
#define NBINS 128
__global__ __launch_bounds__(1024, 4) void k_attn(
    const __bf16* __restrict__ qh, const __bf16* __restrict__ ql,
    const __bf16* __restrict__ kh, const __bf16* __restrict__ kl,
    const __bf16* __restrict__ vv, __bf16* __restrict__ ah,
    __bf16* __restrict__ al) {
  __shared__ unsigned int cand[64][CAP];      // 124 KB packed entries
  __shared__ unsigned int hist[16][NBINS];    //   8 KB (wave-local)
  __shared__ unsigned int blist[16][48];      //   3 KB (wave-local)
  __shared__ float rsum[64], rsum2[64], t0s[64], invq[64], dqs[64], mrefs[64];
  __shared__ unsigned int ccnt[64];
  __shared__ unsigned int bcnt[16];

  const int tid = threadIdx.x;
  const int lane = tid & 63;
  const int wave = tid >> 6;
  const int m15 = lane & 15, q4 = lane >> 4;
  const int rt = wave & 3;       // row-tile 0..3 (16 rows each)
  const int cr = wave >> 2;      // col-range 0..3 (1024 cols each)
  const int cbase = cr * 1024;

  // XCD-locality: XCD x handles bh in {2x, 2x+1}
  const int L = blockIdx.x;      // 1024 blocks
  const int s = L >> 3;          // 0..127
  const int bh = (L & 7) * 2 + (s >> 6);
  const int row0 = (s & 63) * 64;
  const size_t base = (size_t)bh * 4096 * 64;

  if (tid < 64) { rsum[tid] = 0.f; rsum2[tid] = 0.f; ccnt[tid] = 0; }
  __syncthreads();

  // ---- Q fragments for rows row0 + rt*16 + {0..15} ----
  bf16x8 qfh[2], qfl[2];
  {
    const size_t qo = base + (size_t)(row0 + rt * 16 + m15) * 64 + q4 * 8;
    qfh[0] = *(const bf16x8*)(qh + qo);
    qfl[0] = *(const bf16x8*)(ql + qo);
    qfh[1] = *(const bf16x8*)(qh + qo + 32);
    qfl[1] = *(const bf16x8*)(ql + qo + 32);
  }
  const __bf16* kh_b = kh + base;
  const __bf16* kl_b = kl + base;

  // ---- Sample phase: 16 of this wave's 64 tiles -> 1024 samples/row ----
  {
    float s1[4] = {0.f, 0.f, 0.f, 0.f}, s2[4] = {0.f, 0.f, 0.f, 0.f};
    for (int j = 0; j < 16; ++j) {
      const int t = j * 4;
      const size_t ko = (size_t)(cbase + t * 16 + m15) * 64 + q4 * 8;
      const bf16x8 ch0 = *(const bf16x8*)(kh_b + ko);
      const bf16x8 cl0 = *(const bf16x8*)(kl_b + ko);
      const bf16x8 ch1 = *(const bf16x8*)(kh_b + ko + 32);
      const bf16x8 cl1 = *(const bf16x8*)(kl_b + ko + 32);
      f32x4 a = {0.f, 0.f, 0.f, 0.f};
      a = MFMA16(qfh[0], ch0, a);
      a = MFMA16(qfh[1], ch1, a);
      a = MFMA16(qfh[0], cl0, a);
      a = MFMA16(qfh[1], cl1, a);
      a = MFMA16(qfl[0], ch0, a);
      a = MFMA16(qfl[1], ch1, a);
#pragma unroll
      for (int r = 0; r < 4; ++r) { s1[r] += a[r]; s2[r] += a[r] * a[r]; }
    }
#pragma unroll
    for (int o = 1; o < 16; o <<= 1)
#pragma unroll
      for (int r = 0; r < 4; ++r) {
        s1[r] += __shfl_xor(s1[r], o);
        s2[r] += __shfl_xor(s2[r], o);
      }
    if (m15 == 0) {
#pragma unroll
      for (int r = 0; r < 4; ++r) {
        atomicAdd(&rsum[rt * 16 + q4 * 4 + r], s1[r]);
        atomicAdd(&rsum2[rt * 16 + q4 * 4 + r], s2[r]);
      }
    }
  }
  __syncthreads();
  if (tid < 64) {
    const float mu = rsum[tid] * (1.f / 1024.f);
    float var = rsum2[tid] * (1.f / 1024.f) - mu * mu;
    const float sd = sqrtf(fmaxf(var, 1e-12f));
    t0s[tid] = mu + 1.45f * sd;
    invq[tid] = 1048575.0f / (8.0f * sd);   // q range covers t0 .. t0+8sd
    dqs[tid]  = (8.0f * sd) * (1.0f / 1048576.0f);
    mrefs[tid] = mu + 5.0f * sd;            // exp reference
  }
  __syncthreads();

  float t0r[4], ivr[4];
#pragma unroll
  for (int r = 0; r < 4; ++r) {
    t0r[r] = t0s[rt * 16 + q4 * 4 + r];
    ivr[r] = invq[rt * 16 + q4 * 4 + r];
  }

  // ---- Main sweep: 64 col-tiles per wave; per-lane atomic append ----
  for (int t = 0; t < 64; ++t) {
    const size_t ko = (size_t)(cbase + t * 16 + m15) * 64 + q4 * 8;
    const bf16x8 ch0 = *(const bf16x8*)(kh_b + ko);
    const bf16x8 cl0 = *(const bf16x8*)(kl_b + ko);
    const bf16x8 ch1 = *(const bf16x8*)(kh_b + ko + 32);
    const bf16x8 cl1 = *(const bf16x8*)(kl_b + ko + 32);
    f32x4 a = {0.f, 0.f, 0.f, 0.f};
    a = MFMA16(qfh[0], ch0, a);
    a = MFMA16(qfh[1], ch1, a);
    a = MFMA16(qfh[0], cl0, a);
    a = MFMA16(qfh[1], cl1, a);
    a = MFMA16(qfl[0], ch0, a);
    a = MFMA16(qfl[1], ch1, a);
    const unsigned col = (unsigned)(cbase + t * 16 + m15);
#pragma unroll
    for (int r = 0; r < 4; ++r) {
      const float sc = a[r];
      if (sc > t0r[r]) {
        const int row = rt * 16 + q4 * 4 + r;
        int qv = (int)((sc - t0r[r]) * ivr[r]);
        qv = qv > 0xFFFFF ? 0xFFFFF : qv;
        const unsigned e = ((unsigned)qv << 12) | col;
        const unsigned idx = atomicAdd(&ccnt[row], 1u);
        if (idx < CAP) cand[row][idx] = e;
      }
    }
  }
  __syncthreads();

  // ---- Epilogue: wave w owns rows w*4 .. w*4+3 sequentially ----
  const unsigned long long bel = (1ull << lane) - 1ull;
  for (int j = 0; j < 4; ++j) {
    const int row = wave * 4 + j;
    const unsigned cnt = min(ccnt[row], (unsigned)CAP);
    const float t0 = t0s[row], dq = dqs[row], mref = mrefs[row];

    // wave-local histogram over bins = q>>13 (= entry>>25)
    hist[wave][lane] = 0;
    hist[wave][lane + 64] = 0;
    if (lane == 0) bcnt[wave] = 0;
    for (unsigned i = lane; i < cnt; i += 64)
      atomicAdd(&hist[wave][cand[row][i] >> 25], 1u);

    // suffix scan of 128 bins (lane owns bins 2l, 2l+1)
    const unsigned h0 = hist[wave][2 * lane];
    const unsigned h1 = hist[wave][2 * lane + 1];
    unsigned S = h0 + h1;
    for (int o = 1; o < 64; o <<= 1) {
      const unsigned tmp = __shfl_down(S, o);
      if (lane + o < 64) S += tmp;
    }
    unsigned Snext = __shfl_down(S, 1);
    if (lane == 63) Snext = 0;
    const bool owner = (S >= 128u) && (Snext < 128u);
    const unsigned long long msk = __ballot(owner);
    unsigned thrE = 0;
    if (msk != 0ull) {
      const int ol = __ffsll((unsigned long long)msk) - 1;
      int Bv = 0;
      unsigned rv = 128;
      if (owner) {
        if (Snext + h1 >= 128u) { Bv = 2 * lane + 1; rv = 128u - Snext; }
        else { Bv = 2 * lane; rv = 128u - (Snext + h1); }
      }
      const int B = __shfl(Bv, ol);
      const unsigned rneed = (unsigned)__shfl((int)rv, ol);
      // collect bin-B entries (unique uints -> exact rank select)
      for (unsigned i = lane; i < cnt; i += 64) {
        const unsigned e = cand[row][i];
        if ((int)(e >> 25) == B) {
          const unsigned u = atomicAdd(&bcnt[wave], 1u);
          if (u < 48) blist[wave][u] = e;
        }
      }
      const unsigned ml = min(bcnt[wave], 48u);
      const unsigned mye = (lane < (int)ml) ? blist[wave][lane] : 0u;
      unsigned rlt = 0;
      for (unsigned jj = 0; jj < ml; ++jj)
        rlt += (blist[wave][jj] > mye) ? 1u : 0u;
      const bool hit = (lane < (int)ml) && (rlt == rneed - 1u);
      const unsigned long long hm = __ballot(hit);
      if (hm != 0ull) thrE = __shfl(mye, __ffsll((unsigned long long)hm) - 1);
    }

    // compact (e >= thrE -> exactly Snext+rneed = 128 selected)
    unsigned outc = 0;
    float zpart = 0.f;
    for (unsigned c = 0; c * 64 < cnt; ++c) {
      const unsigned i = c * 64 + lane;
      bool sl = false;
      unsigned e = 0;
      if (i < cnt) { e = cand[row][i]; sl = (e >= thrE); }
      const unsigned long long mb = __ballot(sl);
      if (sl) {
        const unsigned pos = outc + (unsigned)__popcll(mb & bel);
        const float scr = t0 + (float)(e >> 12) * dq;
        const float p = __expf(scr - mref);
        zpart += p;
        // pack col into low 12 mantissa bits of p (2.4e-4 rel noise)
        cand[row][pos] = (__float_as_uint(p) & 0xFFFFF000u) | (e & 0xFFFu);
      }
      outc += (unsigned)__popcll(mb);
    }
#pragma unroll
    for (int o = 1; o < 64; o <<= 1) zpart += __shfl_xor(zpart, o);
    const int n = (int)outc;

    // sparse PV gather: lane = dim; batches of 8
    {
      const char* vb2 = (const char*)(vv + base) + lane * 2;
      float o8[8] = {0.f, 0.f, 0.f, 0.f, 0.f, 0.f, 0.f, 0.f};
      int i = 0;
      for (; i + 8 <= n; i += 8) {
        unsigned e0 = cand[row][i + 0], e1 = cand[row][i + 1];
        unsigned e2 = cand[row][i + 2], e3 = cand[row][i + 3];
        unsigned e4 = cand[row][i + 4], e5 = cand[row][i + 5];
        unsigned e6 = cand[row][i + 6], e7 = cand[row][i + 7];
        const unsigned r0 = *(const unsigned short*)(vb2 + (size_t)(e0 & 0xFFFu) * 128);
        const unsigned r1 = *(const unsigned short*)(vb2 + (size_t)(e1 & 0xFFFu) * 128);
        const unsigned r2 = *(const unsigned short*)(vb2 + (size_t)(e2 & 0xFFFu) * 128);
        const unsigned r3 = *(const unsigned short*)(vb2 + (size_t)(e3 & 0xFFFu) * 128);
        const unsigned r4 = *(const unsigned short*)(vb2 + (size_t)(e4 & 0xFFFu) * 128);
        const unsigned r5 = *(const unsigned short*)(vb2 + (size_t)(e5 & 0xFFFu) * 128);
        const unsigned r6 = *(const unsigned short*)(vb2 + (size_t)(e6 & 0xFFFu) * 128);
        const unsigned r7 = *(const unsigned short*)(vb2 + (size_t)(e7 & 0xFFFu) * 128);
        o8[0] += __uint_as_float(e0 & 0xFFFFF000u) * bf16raw_to_f32(r0);
        o8[1] += __uint_as_float(e1 & 0xFFFFF000u) * bf16raw_to_f32(r1);
        o8[2] += __uint_as_float(e2 & 0xFFFFF000u) * bf16raw_to_f32(r2);
        o8[3] += __uint_as_float(e3 & 0xFFFFF000u) * bf16raw_to_f32(r3);
        o8[4] += __uint_as_float(e4 & 0xFFFFF000u) * bf16raw_to_f32(r4);
        o8[5] += __uint_as_float(e5 & 0xFFFFF000u) * bf16raw_to_f32(r5);
        o8[6] += __uint_as_float(e6 & 0xFFFFF000u) * bf16raw_to_f32(r6);
        o8[7] += __uint_as_float(e7 & 0xFFFFF000u) * bf16raw_to_f32(r7);
      }
      for (; i < n; ++i) {
        const unsigned e = cand[row][i];
        const unsigned rr = *(const unsigned short*)(vb2 + (size_t)(e & 0xFFFu) * 128);
        o8[0] += __uint_as_float(e & 0xFFFFF000u) * bf16raw_to_f32(rr);
      }
      const float tot = ((o8[0] + o8[1]) + (o8[2] + o8[3])) +
                        ((o8[4] + o8[5]) + (o8[6] + o8[7]));
      const float outv = tot / fmaxf(zpart, 1e-30f);
      const int b = bh >> 3, hh2 = bh & 7;
      const size_t off =
          ((size_t)(b * 4096 + row0 + row)) * 512 + hh2 * 64 + lane;
      const __bf16 hi = (__bf16)outv;
      ah[off] = hi;
      al[off] = (__bf16)(outv - (float)hi);
    }
  }
}

// ---------------------------------------------------------------------------
extern "C" void kernel_launch(void* const* d_in, const int* in_sizes, int n_in,
                              void* d_out, int out_size, void* d_ws, size_t ws_size,
                              hipStream_t stream) {
  const float* x      = (const float*)d_in[0];
  const float* qkv_w  = (const float*)d_in[1];
  const float* qkv_b  = (const float*)d_in[2];
  const float* proj_w = (const float*)d_in[3];
  const float* proj_b = (const float*)d_in[4];
  float* out = (float*)d_out;

  char* w = (char*)d_ws;
  __bf16* xh  = (__bf16*)(w + 0);          // 8 MiB  (reused as attn_out hi)
  __bf16* xl  = (__bf16*)(w + 8388608);    // 8 MiB  (reused as attn_out lo)
  __bf16* wqh = (__bf16*)(w + 16777216);   // 1.5 MiB  qkv_w^T hi [1536][512]
  __bf16* wql = (__bf16*)(w + 18350080);
  __bf16* wph = (__bf16*)(w + 19922944);   // 0.5 MiB  proj_w^T hi [512][512]
  __bf16* wpl = (__bf16*)(w + 20447232);
  __bf16* Qh  = (__bf16*)(w + 20971520);   // 8 MiB each: [16][4096][64]
  __bf16* Ql  = (__bf16*)(w + 29360128);
  __bf16* Kh  = (__bf16*)(w + 37748736);
  __bf16* Kl  = (__bf16*)(w + 46137344);
  __bf16* Vv  = (__bf16*)(w + 54525952);   // 8 MiB bf16

  // 1) split inputs
  k_split<<<4096, 256, 0, stream>>>(x, xh, xl, 4194304);
  k_splitT<<<(1536 * 512) / 256, 256, 0, stream>>>(qkv_w, wqh, wql, 1536);
  k_splitT<<<(512 * 512) / 256, 256, 0, stream>>>(proj_w, wph, wpl, 512);

  // 2) QKV GEMM (scatter epilogue)
  {
    dim3 g(64, 12);
    k_gemm<0><<<g, 256, 0, stream>>>(xh, xl, wqh, wql, qkv_b, nullptr,
                                     Qh, Ql, Kh, Kl, Vv, 1536, 512);
  }

  // 3) fused top-128 attention (64 rows/block; writes split attn_out)
  k_attn<<<1024, 1024, 0, stream>>>(Qh, Ql, Kh, Kl, Vv, xh, xl);

  // 4) output projection
  {
    dim3 g(64, 4);
    k_gemm<1><<<g, 256, 0, stream>>>(xh, xl, wph, wpl, proj_b, out,
                                     nullptr, nullptr, nullptr, nullptr, nullptr,
                                     512, 512);
  }
}

// Round 8
// 823.799 us; speedup vs baseline: 1.2818x; 1.0774x over previous
//
#include <hip/hip_runtime.h>
#include <cstdint>
#include <cstddef>

// ---------------------------------------------------------------------------
// OptimizedTopMAttention: B=2, N=4096, C=512, H=8, hd=64, TOP_M=128, fp32 I/O.
// Split-precision bf16x2 MFMA for all GEMMs (hh+hl+lh).
// Attention v8 (synthesis): 32 rows/block, 2048 blocks -> 2 resident
// blocks/CU (cross-block phase overlap, the R4-vs-R7 discriminator) at 92%
// occupancy, with R7's 4-B packed candidates (q20<<12|col12, CAP 432) and
// 2x lower K traffic than R4. Exact top-128 via sampled threshold (1024
// samples, 6.9-sigma miss margin) + histogram + exact rank select.
// ---------------------------------------------------------------------------

typedef float f32x4 __attribute__((ext_vector_type(4)));
typedef __bf16 bf16x8 __attribute__((ext_vector_type(8)));
typedef __bf16 bf16x4 __attribute__((ext_vector_type(4)));

#define MFMA16(a, b, c) __builtin_amdgcn_mfma_f32_16x16x32_bf16((a), (b), (c), 0, 0, 0)

static __device__ __forceinline__ void async_ld16(const void* g, void* l) {
  __builtin_amdgcn_global_load_lds(
      (const __attribute__((address_space(1))) unsigned int*)g,
      (__attribute__((address_space(3))) unsigned int*)l, 16, 0, 0);
}

static __device__ __forceinline__ float bf16raw_to_f32(unsigned r) {
  return __uint_as_float(r << 16);
}

// ---------------- split fp32 -> (hi, lo) bf16 ------------------------------
__global__ void k_split(const float* __restrict__ src, __bf16* __restrict__ dh,
                        __bf16* __restrict__ dl, int n) {
  const int i = (blockIdx.x * 256 + threadIdx.x) * 4;
  if (i >= n) return;
  const float4 v = *(const float4*)(src + i);
  bf16x4 h, l;
  h[0] = (__bf16)v.x; l[0] = (__bf16)(v.x - (float)h[0]);
  h[1] = (__bf16)v.y; l[1] = (__bf16)(v.y - (float)h[1]);
  h[2] = (__bf16)v.z; l[2] = (__bf16)(v.z - (float)h[2]);
  h[3] = (__bf16)v.w; l[3] = (__bf16)(v.w - (float)h[3]);
  *(bf16x4*)(dh + i) = h;
  *(bf16x4*)(dl + i) = l;
}

// split + transpose: src[512][N] -> dh/dl [N][512]   (K fixed = 512)
__global__ void k_splitT(const float* __restrict__ src, __bf16* __restrict__ dh,
                         __bf16* __restrict__ dl, int N) {
  const int idx = blockIdx.x * 256 + threadIdx.x;
  const int k = idx & 511;
  const int n = idx >> 9;
  if (n >= N) return;
  const float v = src[(size_t)k * N + n];
  const __bf16 hi = (__bf16)v;
  dh[idx] = hi;
  dl[idx] = (__bf16)(v - (float)hi);
}

// ---------------- split-precision GEMM:  C[M][N] = A[M][K] @ B[N][K]^T ------
// MODE 0: QKV epilogue (scatter q*0.125 hi/lo, k hi/lo, v bf16)
// MODE 1: proj epilogue (+bias, fp32 out)
template <int MODE>
__global__ __launch_bounds__(256, 2) void k_gemm(
    const __bf16* __restrict__ Agh, const __bf16* __restrict__ Agl,
    const __bf16* __restrict__ Bgh, const __bf16* __restrict__ Bgl,
    const float* __restrict__ bias, float* __restrict__ Cout,
    __bf16* __restrict__ qh, __bf16* __restrict__ ql,
    __bf16* __restrict__ kh, __bf16* __restrict__ kl,
    __bf16* __restrict__ vv, int N, int K) {
  __shared__ __bf16 sAh[4096], sAl[4096], sBh[4096], sBl[4096];

  const int tid = threadIdx.x;
  const int lane = tid & 63;
  const int wave = tid >> 6;
  const int wm = wave >> 1, wn = wave & 1;
  const int row0 = blockIdx.x * 128;
  const int col0 = blockIdx.y * 128;
  const int m15 = lane & 15, q4 = lane >> 4;

  f32x4 acc[4][4] = {};

  for (int k0 = 0; k0 < K; k0 += 32) {
    __syncthreads();
#pragma unroll
    for (int c = 0; c < 2; ++c) {
      const int s = c * 4 + wave;
      const int gr = s * 16 + m15;
      const int gk = k0 + q4 * 8;
      const size_t aoff = (size_t)(row0 + gr) * K + gk;
      const size_t boff = (size_t)(col0 + gr) * K + gk;
      const int lb = s * 512;
      async_ld16(Agh + aoff, sAh + lb);
      async_ld16(Agl + aoff, sAl + lb);
      async_ld16(Bgh + boff, sBh + lb);
      async_ld16(Bgl + boff, sBl + lb);
    }
    __syncthreads();

    bf16x8 afh[4], afl[4];
#pragma unroll
    for (int mt = 0; mt < 4; ++mt) {
      const int o = (wm * 4 + mt) * 512 + lane * 8;
      afh[mt] = *(const bf16x8*)(sAh + o);
      afl[mt] = *(const bf16x8*)(sAl + o);
    }
#pragma unroll
    for (int nt = 0; nt < 4; ++nt) {
      const int o = (wn * 4 + nt) * 512 + lane * 8;
      const bf16x8 bfh = *(const bf16x8*)(sBh + o);
      const bf16x8 bfl = *(const bf16x8*)(sBl + o);
#pragma unroll
      for (int mt = 0; mt < 4; ++mt) {
        acc[mt][nt] = MFMA16(afh[mt], bfh, acc[mt][nt]);
        acc[mt][nt] = MFMA16(afh[mt], bfl, acc[mt][nt]);
        acc[mt][nt] = MFMA16(afl[mt], bfh, acc[mt][nt]);
      }
    }
  }

#pragma unroll
  for (int mt = 0; mt < 4; ++mt) {
#pragma unroll
    for (int nt = 0; nt < 4; ++nt) {
      const int col = col0 + wn * 64 + nt * 16 + m15;
      const float bcol = bias[col];
#pragma unroll
      for (int r = 0; r < 4; ++r) {
        const int row = row0 + wm * 64 + mt * 16 + q4 * 4 + r;
        const float val = acc[mt][nt][r] + bcol;
        if (MODE == 1) {
          Cout[(size_t)row * N + col] = val;
        } else {
          const int t = col >> 9;       // 0=q 1=k 2=v
          const int cc = col & 511;
          const int h = cc >> 6, d = cc & 63;
          const int b = row >> 12, n = row & 4095;
          const size_t o = ((size_t)(b * 8 + h) * 4096 + n) * 64 + d;
          if (t == 2) {
            vv[o] = (__bf16)val;
          } else {
            const float sv = (t == 0) ? val * 0.125f : val;  // fold 1/sqrt(hd)
            const __bf16 hi = (__bf16)sv;
            const __bf16 lo = (__bf16)(sv - (float)hi);
            if (t == 0) { qh[o] = hi; ql[o] = lo; }
            else        { kh[o] = hi; kl[o] = lo; }
          }
        }
      }
    }
  }
}

// ---------------- fused top-M attention: 32 rows/block, 2 blocks/CU --------
// t0 = mu + 1.45*sd (1024 samples): 6.9-sigma miss margin vs z128=1.862.
// E[cnt]=301, sd=16.7 -> CAP 432 = +7.8 sigma overflow margin.
// Packed entry: (q<<12)|col, q = (s-t0)*invq in [0,2^20).
#define CAP 432
#define NBINS 128
__global__ __launch_bounds__(1024, 8) void k_attn(
    const __bf16* __restrict__ qh, const __bf16* __restrict__ ql,
    const __bf16* __restrict__ kh, const __bf16* __restrict__ kl,
    const __bf16* __restrict__ vv, __bf16* __restrict__ ah,
    __bf16* __restrict__ al) {
  __shared__ unsigned int cand[32][CAP];      // 55.3 KB packed entries
  __shared__ unsigned int hist[16][NBINS];    //  8 KB (wave-local)
  __shared__ unsigned int blist[16][48];      //  3 KB (wave-local)
  __shared__ float rsum[32], rsum2[32], t0s[32], invq[32], dqs[32], mrefs[32];
  __shared__ unsigned int ccnt[32];
  __shared__ unsigned int bcnt[16];

  const int tid = threadIdx.x;
  const int lane = tid & 63;
  const int wave = tid >> 6;
  const int m15 = lane & 15, q4 = lane >> 4;
  const int rt = wave & 1;       // row-tile 0..1 (16 rows each)
  const int cr = wave >> 1;      // col-range 0..7 (512 cols each)
  const int cbase = cr * 512;

  // XCD-locality: XCD x handles bh in {2x, 2x+1}
  const int L = blockIdx.x;      // 2048 blocks
  const int s = L >> 3;          // 0..255
  const int bh = (L & 7) * 2 + (s >> 7);
  const int row0 = (s & 127) * 32;
  const size_t base = (size_t)bh * 4096 * 64;

  if (tid < 32) { rsum[tid] = 0.f; rsum2[tid] = 0.f; ccnt[tid] = 0; }
  __syncthreads();

  // ---- Q fragments for rows row0 + rt*16 + {0..15} ----
  bf16x8 qfh[2], qfl[2];
  {
    const size_t qo = base + (size_t)(row0 + rt * 16 + m15) * 64 + q4 * 8;
    qfh[0] = *(const bf16x8*)(qh + qo);
    qfl[0] = *(const bf16x8*)(ql + qo);
    qfh[1] = *(const bf16x8*)(qh + qo + 32);
    qfl[1] = *(const bf16x8*)(ql + qo + 32);
  }
  const __bf16* kh_b = kh + base;
  const __bf16* kl_b = kl + base;

  // ---- Sample phase: 8 of this wave's 32 tiles -> 1024 samples/row ----
  {
    float s1[4] = {0.f, 0.f, 0.f, 0.f}, s2[4] = {0.f, 0.f, 0.f, 0.f};
    for (int j = 0; j < 8; ++j) {
      const int t = j * 4;
      const size_t ko = (size_t)(cbase + t * 16 + m15) * 64 + q4 * 8;
      const bf16x8 ch0 = *(const bf16x8*)(kh_b + ko);
      const bf16x8 cl0 = *(const bf16x8*)(kl_b + ko);
      const bf16x8 ch1 = *(const bf16x8*)(kh_b + ko + 32);
      const bf16x8 cl1 = *(const bf16x8*)(kl_b + ko + 32);
      f32x4 a = {0.f, 0.f, 0.f, 0.f};
      a = MFMA16(qfh[0], ch0, a);
      a = MFMA16(qfh[1], ch1, a);
      a = MFMA16(qfh[0], cl0, a);
      a = MFMA16(qfh[1], cl1, a);
      a = MFMA16(qfl[0], ch0, a);
      a = MFMA16(qfl[1], ch1, a);
#pragma unroll
      for (int r = 0; r < 4; ++r) { s1[r] += a[r]; s2[r] += a[r] * a[r]; }
    }
#pragma unroll
    for (int o = 1; o < 16; o <<= 1)
#pragma unroll
      for (int r = 0; r < 4; ++r) {
        s1[r] += __shfl_xor(s1[r], o);
        s2[r] += __shfl_xor(s2[r], o);
      }
    if (m15 == 0) {
#pragma unroll
      for (int r = 0; r < 4; ++r) {
        atomicAdd(&rsum[rt * 16 + q4 * 4 + r], s1[r]);
        atomicAdd(&rsum2[rt * 16 + q4 * 4 + r], s2[r]);
      }
    }
  }
  __syncthreads();
  if (tid < 32) {
    const float mu = rsum[tid] * (1.f / 1024.f);
    float var = rsum2[tid] * (1.f / 1024.f) - mu * mu;
    const float sd = sqrtf(fmaxf(var, 1e-12f));
    t0s[tid] = mu + 1.45f * sd;
    invq[tid] = 1048575.0f / (8.0f * sd);   // q range covers t0 .. t0+8sd
    dqs[tid]  = (8.0f * sd) * (1.0f / 1048576.0f);
    mrefs[tid] = mu + 5.0f * sd;            // exp reference
  }
  __syncthreads();

  float t0r[4], ivr[4];
#pragma unroll
  for (int r = 0; r < 4; ++r) {
    t0r[r] = t0s[rt * 16 + q4 * 4 + r];
    ivr[r] = invq[rt * 16 + q4 * 4 + r];
  }

  // ---- Main sweep: 32 col-tiles per wave; per-lane atomic append ----
  for (int t = 0; t < 32; ++t) {
    const size_t ko = (size_t)(cbase + t * 16 + m15) * 64 + q4 * 8;
    const bf16x8 ch0 = *(const bf16x8*)(kh_b + ko);
    const bf16x8 cl0 = *(const bf16x8*)(kl_b + ko);
    const bf16x8 ch1 = *(const bf16x8*)(kh_b + ko + 32);
    const bf16x8 cl1 = *(const bf16x8*)(kl_b + ko + 32);
    f32x4 a = {0.f, 0.f, 0.f, 0.f};
    a = MFMA16(qfh[0], ch0, a);
    a = MFMA16(qfh[1], ch1, a);
    a = MFMA16(qfh[0], cl0, a);
    a = MFMA16(qfh[1], cl1, a);
    a = MFMA16(qfl[0], ch0, a);
    a = MFMA16(qfl[1], ch1, a);
    const unsigned col = (unsigned)(cbase + t * 16 + m15);
#pragma unroll
    for (int r = 0; r < 4; ++r) {
      const float sc = a[r];
      if (sc > t0r[r]) {
        const int row = rt * 16 + q4 * 4 + r;
        int qv = (int)((sc - t0r[r]) * ivr[r]);
        qv = qv > 0xFFFFF ? 0xFFFFF : qv;
        const unsigned e = ((unsigned)qv << 12) | col;
        const unsigned idx = atomicAdd(&ccnt[row], 1u);
        if (idx < CAP) cand[row][idx] = e;
      }
    }
  }
  __syncthreads();

  // ---- Epilogue: wave w owns rows 2w, 2w+1 sequentially ----
  const unsigned long long bel = (1ull << lane) - 1ull;
  for (int j = 0; j < 2; ++j) {
    const int row = wave * 2 + j;
    const unsigned cnt = min(ccnt[row], (unsigned)CAP);
    const float t0 = t0s[row], dq = dqs[row], mref = mrefs[row];

    // wave-local histogram over bins = q>>13 (= entry>>25)
    hist[wave][lane] = 0;
    hist[wave][lane + 64] = 0;
    if (lane == 0) bcnt[wave] = 0;
    for (unsigned i = lane; i < cnt; i += 64)
      atomicAdd(&hist[wave][cand[row][i] >> 25], 1u);

    // suffix scan of 128 bins (lane owns bins 2l, 2l+1)
    const unsigned h0 = hist[wave][2 * lane];
    const unsigned h1 = hist[wave][2 * lane + 1];
    unsigned S = h0 + h1;
    for (int o = 1; o < 64; o <<= 1) {
      const unsigned tmp = __shfl_down(S, o);
      if (lane + o < 64) S += tmp;
    }
    unsigned Snext = __shfl_down(S, 1);
    if (lane == 63) Snext = 0;
    const bool owner = (S >= 128u) && (Snext < 128u);
    const unsigned long long msk = __ballot(owner);
    unsigned thrE = 0;
    if (msk != 0ull) {
      const int ol = __ffsll((unsigned long long)msk) - 1;
      int Bv = 0;
      unsigned rv = 128;
      if (owner) {
        if (Snext + h1 >= 128u) { Bv = 2 * lane + 1; rv = 128u - Snext; }
        else { Bv = 2 * lane; rv = 128u - (Snext + h1); }
      }
      const int B = __shfl(Bv, ol);
      const unsigned rneed = (unsigned)__shfl((int)rv, ol);
      // collect bin-B entries (unique uints -> exact rank select)
      for (unsigned i = lane; i < cnt; i += 64) {
        const unsigned e = cand[row][i];
        if ((int)(e >> 25) == B) {
          const unsigned u = atomicAdd(&bcnt[wave], 1u);
          if (u < 48) blist[wave][u] = e;
        }
      }
      const unsigned ml = min(bcnt[wave], 48u);
      const unsigned mye = (lane < (int)ml) ? blist[wave][lane] : 0u;
      unsigned rlt = 0;
      for (unsigned jj = 0; jj < ml; ++jj)
        rlt += (blist[wave][jj] > mye) ? 1u : 0u;
      const bool hit = (lane < (int)ml) && (rlt == rneed - 1u);
      const unsigned long long hm = __ballot(hit);
      if (hm != 0ull) thrE = __shfl(mye, __ffsll((unsigned long long)hm) - 1);
    }

    // compact (e >= thrE -> exactly 128 selected)
    unsigned outc = 0;
    float zpart = 0.f;
    for (unsigned c = 0; c * 64 < cnt; ++c) {
      const unsigned i = c * 64 + lane;
      bool sl = false;
      unsigned e = 0;
      if (i < cnt) { e = cand[row][i]; sl = (e >= thrE); }
      const unsigned long long mb = __ballot(sl);
      if (sl) {
        const unsigned pos = outc + (unsigned)__popcll(mb & bel);
        const float scr = t0 + (float)(e >> 12) * dq;
        const float p = __expf(scr - mref);
        zpart += p;
        // pack col into low 12 mantissa bits of p (2.4e-4 rel noise)
        cand[row][pos] = (__float_as_uint(p) & 0xFFFFF000u) | (e & 0xFFFu);
      }
      outc += (unsigned)__popcll(mb);
    }
#pragma unroll
    for (int o = 1; o < 64; o <<= 1) zpart += __shfl_xor(zpart, o);
    const int n = (int)outc;

    // sparse PV gather: lane = dim; batches of 8
    {
      const char* vb2 = (const char*)(vv + base) + lane * 2;
      float o8[8] = {0.f, 0.f, 0.f, 0.f, 0.f, 0.f, 0.f, 0.f};
      int i = 0;
      for (; i + 8 <= n; i += 8) {
        unsigned e0 = cand[row][i + 0], e1 = cand[row][i + 1];
        unsigned e2 = cand[row][i + 2], e3 = cand[row][i + 3];
        unsigned e4 = cand[row][i + 4], e5 = cand[row][i + 5];
        unsigned e6 = cand[row][i + 6], e7 = cand[row][i + 7];
        const unsigned r0 = *(const unsigned short*)(vb2 + (size_t)(e0 & 0xFFFu) * 128);
        const unsigned r1 = *(const unsigned short*)(vb2 + (size_t)(e1 & 0xFFFu) * 128);
        const unsigned r2 = *(const unsigned short*)(vb2 + (size_t)(e2 & 0xFFFu) * 128);
        const unsigned r3 = *(const unsigned short*)(vb2 + (size_t)(e3 & 0xFFFu) * 128);
        const unsigned r4 = *(const unsigned short*)(vb2 + (size_t)(e4 & 0xFFFu) * 128);
        const unsigned r5 = *(const unsigned short*)(vb2 + (size_t)(e5 & 0xFFFu) * 128);
        const unsigned r6 = *(const unsigned short*)(vb2 + (size_t)(e6 & 0xFFFu) * 128);
        const unsigned r7 = *(const unsigned short*)(vb2 + (size_t)(e7 & 0xFFFu) * 128);
        o8[0] += __uint_as_float(e0 & 0xFFFFF000u) * bf16raw_to_f32(r0);
        o8[1] += __uint_as_float(e1 & 0xFFFFF000u) * bf16raw_to_f32(r1);
        o8[2] += __uint_as_float(e2 & 0xFFFFF000u) * bf16raw_to_f32(r2);
        o8[3] += __uint_as_float(e3 & 0xFFFFF000u) * bf16raw_to_f32(r3);
        o8[4] += __uint_as_float(e4 & 0xFFFFF000u) * bf16raw_to_f32(r4);
        o8[5] += __uint_as_float(e5 & 0xFFFFF000u) * bf16raw_to_f32(r5);
        o8[6] += __uint_as_float(e6 & 0xFFFFF000u) * bf16raw_to_f32(r6);
        o8[7] += __uint_as_float(e7 & 0xFFFFF000u) * bf16raw_to_f32(r7);
      }
      for (; i < n; ++i) {
        const unsigned e = cand[row][i];
        const unsigned rr = *(const unsigned short*)(vb2 + (size_t)(e & 0xFFFu) * 128);
        o8[0] += __uint_as_float(e & 0xFFFFF000u) * bf16raw_to_f32(rr);
      }
      const float tot = ((o8[0] + o8[1]) + (o8[2] + o8[3])) +
                        ((o8[4] + o8[5]) + (o8[6] + o8[7]));
      const float outv = tot / fmaxf(zpart, 1e-30f);
      const int b = bh >> 3, hh2 = bh & 7;
      const size_t off =
          ((size_t)(b * 4096 + row0 + row)) * 512 + hh2 * 64 + lane;
      const __bf16 hi = (__bf16)outv;
      ah[off] = hi;
      al[off] = (__bf16)(outv - (float)hi);
    }
  }
}

// ---------------------------------------------------------------------------
extern "C" void kernel_launch(void* const* d_in, const int* in_sizes, int n_in,
                              void* d_out, int out_size, void* d_ws, size_t ws_size,
                              hipStream_t stream) {
  const float* x      = (const float*)d_in[0];
  const float* qkv_w  = (const float*)d_in[1];
  const float* qkv_b  = (const float*)d_in[2];
  const float* proj_w = (const float*)d_in[3];
  const float* proj_b = (const float*)d_in[4];
  float* out = (float*)d_out;

  char* w = (char*)d_ws;
  __bf16* xh  = (__bf16*)(w + 0);          // 8 MiB  (reused as attn_out hi)
  __bf16* xl  = (__bf16*)(w + 8388608);    // 8 MiB  (reused as attn_out lo)
  __bf16* wqh = (__bf16*)(w + 16777216);   // 1.5 MiB  qkv_w^T hi [1536][512]
  __bf16* wql = (__bf16*)(w + 18350080);
  __bf16* wph = (__bf16*)(w + 19922944);   // 0.5 MiB  proj_w^T hi [512][512]
  __bf16* wpl = (__bf16*)(w + 20447232);
  __bf16* Qh  = (__bf16*)(w + 20971520);   // 8 MiB each: [16][4096][64]
  __bf16* Ql  = (__bf16*)(w + 29360128);
  __bf16* Kh  = (__bf16*)(w + 37748736);
  __bf16* Kl  = (__bf16*)(w + 46137344);
  __bf16* Vv  = (__bf16*)(w + 54525952);   // 8 MiB bf16

  // 1) split inputs
  k_split<<<4096, 256, 0, stream>>>(x, xh, xl, 4194304);
  k_splitT<<<(1536 * 512) / 256, 256, 0, stream>>>(qkv_w, wqh, wql, 1536);
  k_splitT<<<(512 * 512) / 256, 256, 0, stream>>>(proj_w, wph, wpl, 512);

  // 2) QKV GEMM (scatter epilogue)
  {
    dim3 g(64, 12);
    k_gemm<0><<<g, 256, 0, stream>>>(xh, xl, wqh, wql, qkv_b, nullptr,
                                     Qh, Ql, Kh, Kl, Vv, 1536, 512);
  }

  // 3) fused top-128 attention (32 rows/block; writes split attn_out)
  k_attn<<<2048, 1024, 0, stream>>>(Qh, Ql, Kh, Kl, Vv, xh, xl);

  // 4) output projection
  {
    dim3 g(64, 4);
    k_gemm<1><<<g, 256, 0, stream>>>(xh, xl, wph, wpl, proj_b, out,
                                     nullptr, nullptr, nullptr, nullptr, nullptr,
                                     512, 512);
  }
}

// Round 10
// 466.253 us; speedup vs baseline: 2.2647x; 1.7668x over previous
//
#include <hip/hip_runtime.h>
#include <cstdint>
#include <cstddef>

// ---------------------------------------------------------------------------
// OptimizedTopMAttention: B=2, N=4096, C=512, H=8, hd=64, TOP_M=128, fp32 I/O.
// Split-precision bf16x2 MFMA for all GEMMs (hh+hl+lh).
// Attention v9: K stored in MFMA-FRAGMENT TILE ORDER (4 KB blocks
// [ch0|ch1|cl0|cl1], lane-linear 16 B) -> the sweep's 4 loads/tile are fully
// coalesced (8 used lines vs 16 half-used with the [n][64] layout). This
// attacks the R4/R7/R8 invariant: ~84 cyc/load from 16-segment scattered
// fragment loads. Selection machinery identical to R8 (passed, 32 VGPR):
// 32 rows/block, packed q20|col12 candidates, sampled threshold
// (6.9-sigma margins), histogram + exact rank select, batched PV gather.
// ---------------------------------------------------------------------------

typedef float f32x4 __attribute__((ext_vector_type(4)));
typedef __bf16 bf16x8 __attribute__((ext_vector_type(8)));
typedef __bf16 bf16x4 __attribute__((ext_vector_type(4)));

#define MFMA16(a, b, c) __builtin_amdgcn_mfma_f32_16x16x32_bf16((a), (b), (c), 0, 0, 0)

static __device__ __forceinline__ void async_ld16(const void* g, void* l) {
  __builtin_amdgcn_global_load_lds(
      (const __attribute__((address_space(1))) unsigned int*)g,
      (__attribute__((address_space(3))) unsigned int*)l, 16, 0, 0);
}

static __device__ __forceinline__ float bf16raw_to_f32(unsigned r) {
  return __uint_as_float(r << 16);
}

// ---------------- split fp32 -> (hi, lo) bf16 ------------------------------
__global__ void k_split(const float* __restrict__ src, __bf16* __restrict__ dh,
                        __bf16* __restrict__ dl, int n) {
  const int i = (blockIdx.x * 256 + threadIdx.x) * 4;
  if (i >= n) return;
  const float4 v = *(const float4*)(src + i);
  bf16x4 h, l;
  h[0] = (__bf16)v.x; l[0] = (__bf16)(v.x - (float)h[0]);
  h[1] = (__bf16)v.y; l[1] = (__bf16)(v.y - (float)h[1]);
  h[2] = (__bf16)v.z; l[2] = (__bf16)(v.z - (float)h[2]);
  h[3] = (__bf16)v.w; l[3] = (__bf16)(v.w - (float)h[3]);
  *(bf16x4*)(dh + i) = h;
  *(bf16x4*)(dl + i) = l;
}

// split + transpose: src[512][N] -> dh/dl [N][512]   (K fixed = 512)
__global__ void k_splitT(const float* __restrict__ src, __bf16* __restrict__ dh,
                         __bf16* __restrict__ dl, int N) {
  const int idx = blockIdx.x * 256 + threadIdx.x;
  const int k = idx & 511;
  const int n = idx >> 9;
  if (n >= N) return;
  const float v = src[(size_t)k * N + n];
  const __bf16 hi = (__bf16)v;
  dh[idx] = hi;
  dl[idx] = (__bf16)(v - (float)hi);
}

// ---------------- split-precision GEMM:  C[M][N] = A[M][K] @ B[N][K]^T ------
// MODE 0: QKV epilogue (scatter q*0.125 hi/lo; K in fragment-tile order; v bf16)
// MODE 1: proj epilogue (+bias, fp32 out)
template <int MODE>
__global__ __launch_bounds__(256, 2) void k_gemm(
    const __bf16* __restrict__ Agh, const __bf16* __restrict__ Agl,
    const __bf16* __restrict__ Bgh, const __bf16* __restrict__ Bgl,
    const float* __restrict__ bias, float* __restrict__ Cout,
    __bf16* __restrict__ qh, __bf16* __restrict__ ql,
    __bf16* __restrict__ kf,
    __bf16* __restrict__ vv, int N, int K) {
  __shared__ __bf16 sAh[4096], sAl[4096], sBh[4096], sBl[4096];

  const int tid = threadIdx.x;
  const int lane = tid & 63;
  const int wave = tid >> 6;
  const int wm = wave >> 1, wn = wave & 1;
  const int row0 = blockIdx.x * 128;
  const int col0 = blockIdx.y * 128;
  const int m15 = lane & 15, q4 = lane >> 4;

  f32x4 acc[4][4] = {};

  for (int k0 = 0; k0 < K; k0 += 32) {
    __syncthreads();
#pragma unroll
    for (int c = 0; c < 2; ++c) {
      const int s = c * 4 + wave;
      const int gr = s * 16 + m15;
      const int gk = k0 + q4 * 8;
      const size_t aoff = (size_t)(row0 + gr) * K + gk;
      const size_t boff = (size_t)(col0 + gr) * K + gk;
      const int lb = s * 512;
      async_ld16(Agh + aoff, sAh + lb);
      async_ld16(Agl + aoff, sAl + lb);
      async_ld16(Bgh + boff, sBh + lb);
      async_ld16(Bgl + boff, sBl + lb);
    }
    __syncthreads();

    bf16x8 afh[4], afl[4];
#pragma unroll
    for (int mt = 0; mt < 4; ++mt) {
      const int o = (wm * 4 + mt) * 512 + lane * 8;
      afh[mt] = *(const bf16x8*)(sAh + o);
      afl[mt] = *(const bf16x8*)(sAl + o);
    }
#pragma unroll
    for (int nt = 0; nt < 4; ++nt) {
      const int o = (wn * 4 + nt) * 512 + lane * 8;
      const bf16x8 bfh = *(const bf16x8*)(sBh + o);
      const bf16x8 bfl = *(const bf16x8*)(sBl + o);
#pragma unroll
      for (int mt = 0; mt < 4; ++mt) {
        acc[mt][nt] = MFMA16(afh[mt], bfh, acc[mt][nt]);
        acc[mt][nt] = MFMA16(afh[mt], bfl, acc[mt][nt]);
        acc[mt][nt] = MFMA16(afl[mt], bfh, acc[mt][nt]);
      }
    }
  }

#pragma unroll
  for (int mt = 0; mt < 4; ++mt) {
#pragma unroll
    for (int nt = 0; nt < 4; ++nt) {
      const int col = col0 + wn * 64 + nt * 16 + m15;
      const float bcol = bias[col];
#pragma unroll
      for (int r = 0; r < 4; ++r) {
        const int row = row0 + wm * 64 + mt * 16 + q4 * 4 + r;
        const float val = acc[mt][nt][r] + bcol;
        if (MODE == 1) {
          Cout[(size_t)row * N + col] = val;
        } else {
          const int t = col >> 9;       // 0=q 1=k 2=v
          const int cc = col & 511;
          const int h = cc >> 6, d = cc & 63;
          const int b = row >> 12, n = row & 4095;
          const int bh2 = b * 8 + h;
          if (t == 2) {
            vv[((size_t)bh2 * 4096 + n) * 64 + d] = (__bf16)val;
          } else if (t == 0) {
            const float sv = val * 0.125f;        // fold 1/sqrt(hd)
            const __bf16 hi = (__bf16)sv;
            const size_t o = ((size_t)bh2 * 4096 + n) * 64 + d;
            qh[o] = hi;
            ql[o] = (__bf16)(sv - (float)hi);
          } else {
            // K in fragment-tile order: 4x512-elem blocks per 16-col tile:
            // f0=ch0(hi,d<32) f1=ch1(hi,d>=32) f2=cl0 f3=cl1; within block,
            // element (col m, dim d): idx = (q4e*16 + m)*8 + e, q4e=(d&31)>>3.
            const int tt = n >> 4, m = n & 15;
            const int half = d >> 5, q4e = (d & 31) >> 3, e = d & 7;
            const size_t o = ((size_t)(bh2 * 256 + tt) * 4 + half) * 512 +
                             (q4e * 16 + m) * 8 + e;
            const __bf16 hi = (__bf16)val;
            kf[o] = hi;
            kf[o + 1024] = (__bf16)(val - (float)hi);
          }
        }
      }
    }
  }
}

// ---------------- fused top-M attention: 32 rows/block, 2 blocks/CU --------
// t0 = mu + 1.45*sd (1024 samples): 6.9-sigma miss margin vs z128=1.862.
// E[cnt]=301, sd=16.7 -> CAP 432 = +7.8 sigma overflow margin.
// Packed entry: (q<<12)|col, q = (s-t0)*invq in [0,2^20).
#define CAP 432
#define NBINS 128
__global__ __launch_bounds__(1024, 8) void k_attn(
    const __bf16* __restrict__ qh, const __bf16* __restrict__ ql,
    const __bf16* __restrict__ kf,
    const __bf16* __restrict__ vv, __bf16* __restrict__ ah,
    __bf16* __restrict__ al) {
  __shared__ unsigned int cand[32][CAP];      // 55.3 KB packed entries
  __shared__ unsigned int hist[16][NBINS];    //  8 KB (wave-local)
  __shared__ unsigned int blist[16][48];      //  3 KB (wave-local)
  __shared__ float rsum[32], rsum2[32], t0s[32], invq[32], dqs[32], mrefs[32];
  __shared__ unsigned int ccnt[32];
  __shared__ unsigned int bcnt[16];

  const int tid = threadIdx.x;
  const int lane = tid & 63;
  const int wave = tid >> 6;
  const int m15 = lane & 15, q4 = lane >> 4;
  const int rt = wave & 1;       // row-tile 0..1 (16 rows each)
  const int cr = wave >> 1;      // col-range 0..7 (512 cols each)
  const int cbase = cr * 512;

  // XCD-locality: XCD x handles bh in {2x, 2x+1}
  const int L = blockIdx.x;      // 2048 blocks
  const int s = L >> 3;          // 0..255
  const int bh = (L & 7) * 2 + (s >> 7);
  const int row0 = (s & 127) * 32;
  const size_t base = (size_t)bh * 4096 * 64;

  if (tid < 32) { rsum[tid] = 0.f; rsum2[tid] = 0.f; ccnt[tid] = 0; }
  __syncthreads();

  // ---- Q fragments for rows row0 + rt*16 + {0..15} ----
  bf16x8 qfh[2], qfl[2];
  {
    const size_t qo = base + (size_t)(row0 + rt * 16 + m15) * 64 + q4 * 8;
    qfh[0] = *(const bf16x8*)(qh + qo);
    qfl[0] = *(const bf16x8*)(ql + qo);
    qfh[1] = *(const bf16x8*)(qh + qo + 32);
    qfl[1] = *(const bf16x8*)(ql + qo + 32);
  }
  // fragment-tile base for this wave's col range: tiles (cr*32 + t)
  const __bf16* kt_base = kf + ((size_t)(bh * 256 + cr * 32) * 4) * 512;
  const int l8 = lane * 8;

  // ---- Sample phase: 8 of this wave's 32 tiles -> 1024 samples/row ----
  {
    float s1[4] = {0.f, 0.f, 0.f, 0.f}, s2[4] = {0.f, 0.f, 0.f, 0.f};
    for (int j = 0; j < 8; ++j) {
      const __bf16* kt = kt_base + (size_t)(j * 4) * 2048;
      const bf16x8 ch0 = *(const bf16x8*)(kt + l8);
      const bf16x8 ch1 = *(const bf16x8*)(kt + 512 + l8);
      const bf16x8 cl0 = *(const bf16x8*)(kt + 1024 + l8);
      const bf16x8 cl1 = *(const bf16x8*)(kt + 1536 + l8);
      f32x4 a = {0.f, 0.f, 0.f, 0.f};
      a = MFMA16(qfh[0], ch0, a);
      a = MFMA16(qfh[1], ch1, a);
      a = MFMA16(qfh[0], cl0, a);
      a = MFMA16(qfh[1], cl1, a);
      a = MFMA16(qfl[0], ch0, a);
      a = MFMA16(qfl[1], ch1, a);
#pragma unroll
      for (int r = 0; r < 4; ++r) { s1[r] += a[r]; s2[r] += a[r] * a[r]; }
    }
#pragma unroll
    for (int o = 1; o < 16; o <<= 1)
#pragma unroll
      for (int r = 0; r < 4; ++r) {
        s1[r] += __shfl_xor(s1[r], o);
        s2[r] += __shfl_xor(s2[r], o);
      }
    if (m15 == 0) {
#pragma unroll
      for (int r = 0; r < 4; ++r) {
        atomicAdd(&rsum[rt * 16 + q4 * 4 + r], s1[r]);
        atomicAdd(&rsum2[rt * 16 + q4 * 4 + r], s2[r]);
      }
    }
  }
  __syncthreads();
  if (tid < 32) {
    const float mu = rsum[tid] * (1.f / 1024.f);
    float var = rsum2[tid] * (1.f / 1024.f) - mu * mu;
    const float sd = sqrtf(fmaxf(var, 1e-12f));
    t0s[tid] = mu + 1.45f * sd;
    invq[tid] = 1048575.0f / (8.0f * sd);   // q range covers t0 .. t0+8sd
    dqs[tid]  = (8.0f * sd) * (1.0f / 1048576.0f);
    mrefs[tid] = mu + 5.0f * sd;            // exp reference
  }
  __syncthreads();

  float t0r[4], ivr[4];
#pragma unroll
  for (int r = 0; r < 4; ++r) {
    t0r[r] = t0s[rt * 16 + q4 * 4 + r];
    ivr[r] = invq[rt * 16 + q4 * 4 + r];
  }

  // ---- Main sweep: 32 col-tiles per wave; coalesced fragment loads ----
  for (int t = 0; t < 32; ++t) {
    const __bf16* kt = kt_base + (size_t)t * 2048;
    const bf16x8 ch0 = *(const bf16x8*)(kt + l8);
    const bf16x8 ch1 = *(const bf16x8*)(kt + 512 + l8);
    const bf16x8 cl0 = *(const bf16x8*)(kt + 1024 + l8);
    const bf16x8 cl1 = *(const bf16x8*)(kt + 1536 + l8);
    f32x4 a = {0.f, 0.f, 0.f, 0.f};
    a = MFMA16(qfh[0], ch0, a);
    a = MFMA16(qfh[1], ch1, a);
    a = MFMA16(qfh[0], cl0, a);
    a = MFMA16(qfh[1], cl1, a);
    a = MFMA16(qfl[0], ch0, a);
    a = MFMA16(qfl[1], ch1, a);
    const unsigned col = (unsigned)(cbase + t * 16 + m15);
#pragma unroll
    for (int r = 0; r < 4; ++r) {
      const float sc = a[r];
      if (sc > t0r[r]) {
        const int row = rt * 16 + q4 * 4 + r;
        int qv = (int)((sc - t0r[r]) * ivr[r]);
        qv = qv > 0xFFFFF ? 0xFFFFF : qv;
        const unsigned e = ((unsigned)qv << 12) | col;
        const unsigned idx = atomicAdd(&ccnt[row], 1u);
        if (idx < CAP) cand[row][idx] = e;
      }
    }
  }
  __syncthreads();

  // ---- Epilogue: wave w owns rows 2w, 2w+1 sequentially ----
  const unsigned long long bel = (1ull << lane) - 1ull;
  for (int j = 0; j < 2; ++j) {
    const int row = wave * 2 + j;
    const unsigned cnt = min(ccnt[row], (unsigned)CAP);
    const float t0 = t0s[row], dq = dqs[row], mref = mrefs[row];

    // wave-local histogram over bins = q>>13 (= entry>>25)
    hist[wave][lane] = 0;
    hist[wave][lane + 64] = 0;
    if (lane == 0) bcnt[wave] = 0;
    for (unsigned i = lane; i < cnt; i += 64)
      atomicAdd(&hist[wave][cand[row][i] >> 25], 1u);

    // suffix scan of 128 bins (lane owns bins 2l, 2l+1)
    const unsigned h0 = hist[wave][2 * lane];
    const unsigned h1 = hist[wave][2 * lane + 1];
    unsigned S = h0 + h1;
    for (int o = 1; o < 64; o <<= 1) {
      const unsigned tmp = __shfl_down(S, o);
      if (lane + o < 64) S += tmp;
    }
    unsigned Snext = __shfl_down(S, 1);
    if (lane == 63) Snext = 0;
    const bool owner = (S >= 128u) && (Snext < 128u);
    const unsigned long long msk = __ballot(owner);
    unsigned thrE = 0;
    if (msk != 0ull) {
      const int ol = __ffsll((unsigned long long)msk) - 1;
      int Bv = 0;
      unsigned rv = 128;
      if (owner) {
        if (Snext + h1 >= 128u) { Bv = 2 * lane + 1; rv = 128u - Snext; }
        else { Bv = 2 * lane; rv = 128u - (Snext + h1); }
      }
      const int B = __shfl(Bv, ol);
      const unsigned rneed = (unsigned)__shfl((int)rv, ol);
      // collect bin-B entries (unique uints -> exact rank select)
      for (unsigned i = lane; i < cnt; i += 64) {
        const unsigned e = cand[row][i];
        if ((int)(e >> 25) == B) {
          const unsigned u = atomicAdd(&bcnt[wave], 1u);
          if (u < 48) blist[wave][u] = e;
        }
      }
      const unsigned ml = min(bcnt[wave], 48u);
      const unsigned mye = (lane < (int)ml) ? blist[wave][lane] : 0u;
      unsigned rlt = 0;
      for (unsigned jj = 0; jj < ml; ++jj)
        rlt += (blist[wave][jj] > mye) ? 1u : 0u;
      const bool hit = (lane < (int)ml) && (rlt == rneed - 1u);
      const unsigned long long hm = __ballot(hit);
      if (hm != 0ull) thrE = __shfl(mye, __ffsll((unsigned long long)hm) - 1);
    }

    // compact (e >= thrE -> exactly 128 selected)
    unsigned outc = 0;
    float zpart = 0.f;
    for (unsigned c = 0; c * 64 < cnt; ++c) {
      const unsigned i = c * 64 + lane;
      bool sl = false;
      unsigned e = 0;
      if (i < cnt) { e = cand[row][i]; sl = (e >= thrE); }
      const unsigned long long mb = __ballot(sl);
      if (sl) {
        const unsigned pos = outc + (unsigned)__popcll(mb & bel);
        const float scr = t0 + (float)(e >> 12) * dq;
        const float p = __expf(scr - mref);
        zpart += p;
        // pack col into low 12 mantissa bits of p (2.4e-4 rel noise)
        cand[row][pos] = (__float_as_uint(p) & 0xFFFFF000u) | (e & 0xFFFu);
      }
      outc += (unsigned)__popcll(mb);
    }
#pragma unroll
    for (int o = 1; o < 64; o <<= 1) zpart += __shfl_xor(zpart, o);
    const int n = (int)outc;

    // sparse PV gather: lane = dim; batches of 8
    {
      const char* vb2 = (const char*)(vv + base) + lane * 2;
      float o8[8] = {0.f, 0.f, 0.f, 0.f, 0.f, 0.f, 0.f, 0.f};
      int i = 0;
      for (; i + 8 <= n; i += 8) {
        unsigned e0 = cand[row][i + 0], e1 = cand[row][i + 1];
        unsigned e2 = cand[row][i + 2], e3 = cand[row][i + 3];
        unsigned e4 = cand[row][i + 4], e5 = cand[row][i + 5];
        unsigned e6 = cand[row][i + 6], e7 = cand[row][i + 7];
        const unsigned r0 = *(const unsigned short*)(vb2 + (size_t)(e0 & 0xFFFu) * 128);
        const unsigned r1 = *(const unsigned short*)(vb2 + (size_t)(e1 & 0xFFFu) * 128);
        const unsigned r2 = *(const unsigned short*)(vb2 + (size_t)(e2 & 0xFFFu) * 128);
        const unsigned r3 = *(const unsigned short*)(vb2 + (size_t)(e3 & 0xFFFu) * 128);
        const unsigned r4 = *(const unsigned short*)(vb2 + (size_t)(e4 & 0xFFFu) * 128);
        const unsigned r5 = *(const unsigned short*)(vb2 + (size_t)(e5 & 0xFFFu) * 128);
        const unsigned r6 = *(const unsigned short*)(vb2 + (size_t)(e6 & 0xFFFu) * 128);
        const unsigned r7 = *(const unsigned short*)(vb2 + (size_t)(e7 & 0xFFFu) * 128);
        o8[0] += __uint_as_float(e0 & 0xFFFFF000u) * bf16raw_to_f32(r0);
        o8[1] += __uint_as_float(e1 & 0xFFFFF000u) * bf16raw_to_f32(r1);
        o8[2] += __uint_as_float(e2 & 0xFFFFF000u) * bf16raw_to_f32(r2);
        o8[3] += __uint_as_float(e3 & 0xFFFFF000u) * bf16raw_to_f32(r3);
        o8[4] += __uint_as_float(e4 & 0xFFFFF000u) * bf16raw_to_f32(r4);
        o8[5] += __uint_as_float(e5 & 0xFFFFF000u) * bf16raw_to_f32(r5);
        o8[6] += __uint_as_float(e6 & 0xFFFFF000u) * bf16raw_to_f32(r6);
        o8[7] += __uint_as_float(e7 & 0xFFFFF000u) * bf16raw_to_f32(r7);
      }
      for (; i < n; ++i) {
        const unsigned e = cand[row][i];
        const unsigned rr = *(const unsigned short*)(vb2 + (size_t)(e & 0xFFFu) * 128);
        o8[0] += __uint_as_float(e & 0xFFFFF000u) * bf16raw_to_f32(rr);
      }
      const float tot = ((o8[0] + o8[1]) + (o8[2] + o8[3])) +
                        ((o8[4] + o8[5]) + (o8[6] + o8[7]));
      const float outv = tot / fmaxf(zpart, 1e-30f);
      const int b = bh >> 3, hh2 = bh & 7;
      const size_t off =
          ((size_t)(b * 4096 + row0 + row)) * 512 + hh2 * 64 + lane;
      const __bf16 hi = (__bf16)outv;
      ah[off] = hi;
      al[off] = (__bf16)(outv - (float)hi);
    }
  }
}

// ---------------------------------------------------------------------------
extern "C" void kernel_launch(void* const* d_in, const int* in_sizes, int n_in,
                              void* d_out, int out_size, void* d_ws, size_t ws_size,
                              hipStream_t stream) {
  const float* x      = (const float*)d_in[0];
  const float* qkv_w  = (const float*)d_in[1];
  const float* qkv_b  = (const float*)d_in[2];
  const float* proj_w = (const float*)d_in[3];
  const float* proj_b = (const float*)d_in[4];
  float* out = (float*)d_out;

  char* w = (char*)d_ws;
  __bf16* xh  = (__bf16*)(w + 0);          // 8 MiB  (reused as attn_out hi)
  __bf16* xl  = (__bf16*)(w + 8388608);    // 8 MiB  (reused as attn_out lo)
  __bf16* wqh = (__bf16*)(w + 16777216);   // 1.5 MiB  qkv_w^T hi [1536][512]
  __bf16* wql = (__bf16*)(w + 18350080);
  __bf16* wph = (__bf16*)(w + 19922944);   // 0.5 MiB  proj_w^T hi [512][512]
  __bf16* wpl = (__bf16*)(w + 20447232);
  __bf16* Qh  = (__bf16*)(w + 20971520);   // 8 MiB each: [16][4096][64]
  __bf16* Ql  = (__bf16*)(w + 29360128);
  __bf16* Kf  = (__bf16*)(w + 37748736);   // 16 MiB K fragment-tile order
  __bf16* Vv  = (__bf16*)(w + 54525952);   // 8 MiB bf16 [16][4096][64]

  // 1) split inputs
  k_split<<<4096, 256, 0, stream>>>(x, xh, xl, 4194304);
  k_splitT<<<(1536 * 512) / 256, 256, 0, stream>>>(qkv_w, wqh, wql, 1536);
  k_splitT<<<(512 * 512) / 256, 256, 0, stream>>>(proj_w, wph, wpl, 512);

  // 2) QKV GEMM (scatter epilogue; K into fragment-tile layout)
  {
    dim3 g(64, 12);
    k_gemm<0><<<g, 256, 0, stream>>>(xh, xl, wqh, wql, qkv_b, nullptr,
                                     Qh, Ql, Kf, Vv, 1536, 512);
  }

  // 3) fused top-128 attention (32 rows/block; writes split attn_out)
  k_attn<<<2048, 1024, 0, stream>>>(Qh, Ql, Kf, Vv, xh, xl);

  // 4) output projection
  {
    dim3 g(64, 4);
    k_gemm<1><<<g, 256, 0, stream>>>(xh, xl, wph, wpl, proj_b, out,
                                     nullptr, nullptr, nullptr, nullptr,
                                     512, 512);
  }
}